// Round 4
// baseline (269.785 us; speedup 1.0000x reference)
//
#include <hip/hip_runtime.h>

// Attention block: qkv proj -> RoPE -> causal GQA flash attention -> out proj.
// B=1, S=2048, H=2048, NH=32, KVH=8, D=64, G=4.
// R4: flash rework — longest-first block order, 64-key tiles, async double-buffered
//     K/V staging (global_load_lds + XOR swizzle, 1 barrier/tile), ones-frag in
//     registers, masked-quadrant skipping. Gemm128 (R3) unchanged.

typedef __bf16 bf16_t;
typedef __attribute__((ext_vector_type(8))) __bf16 bf16x8;
typedef __attribute__((ext_vector_type(4))) __bf16 bf16x4;
typedef __attribute__((ext_vector_type(4))) float f32x4;

#define S_LEN 2048
#define H_DIM 2048
#define NHEAD 32
#define KVH 8
#define HD 64
#define QKV_N 3072  // (NH + 2*KVH) * D

// ---------------- cast fp32 -> bf16 ----------------
__global__ void cast_kernel(const float* __restrict__ in, bf16_t* __restrict__ out, int n4) {
  int i = blockIdx.x * blockDim.x + threadIdx.x;
  if (i >= n4) return;
  float4 v = ((const float4*)in)[i];
  bf16x4 o;
  o.x = (bf16_t)v.x; o.y = (bf16_t)v.y; o.z = (bf16_t)v.z; o.w = (bf16_t)v.w;
  ((bf16x4*)out)[i] = o;
}

// ---------------- async 16B global -> LDS ----------------
__device__ __forceinline__ void async_copy16(bf16_t* lds_base, const bf16_t* g) {
  __builtin_amdgcn_global_load_lds(
      (const __attribute__((address_space(1))) unsigned int*)g,
      (__attribute__((address_space(3))) unsigned int*)lds_base, 16, 0, 0);
}

// ---------------- GEMM: C[M,N] = A[M,K] * B[N,K]^T (bf16 in, fp32 out) ----------------
#define TBM 128
#define TBN 128
#define TBK 32

__global__ __launch_bounds__(256) void gemm128(const bf16_t* __restrict__ A,
                                               const bf16_t* __restrict__ B,
                                               float* __restrict__ C,
                                               int M, int N, int K) {
  __shared__ __align__(16) bf16_t As[2][TBM * TBK];
  __shared__ __align__(16) bf16_t Bs[2][TBM * TBK];

  const int tid  = threadIdx.x;
  const int lane = tid & 63;
  const int w    = tid >> 6;
  const int wm   = (w >> 1) * 64;
  const int wn   = (w & 1) * 64;
  const int c    = lane & 15;
  const int quad = lane >> 4;
  const int m0   = blockIdx.y * TBM;
  const int n0   = blockIdx.x * TBN;

  f32x4 acc[4][4] = {};

  const bf16_t* Ab = A + (size_t)m0 * K;
  const bf16_t* Bb = B + (size_t)n0 * K;

  int srow[2], skch[2], sbase[2];
#pragma unroll
  for (int i = 0; i < 2; ++i) {
    int chunkbase = i * 256 + w * 64;
    int chunk = chunkbase + lane;
    sbase[i] = chunkbase * 8;
    srow[i]  = chunk >> 2;
    skch[i]  = (chunk & 3) ^ ((chunk >> 3) & 3);
  }

  auto stage = [&](int buf, int k0) {
#pragma unroll
    for (int i = 0; i < 2; ++i) {
      const bf16_t* ga = Ab + (size_t)srow[i] * K + k0 + skch[i] * 8;
      const bf16_t* gb = Bb + (size_t)srow[i] * K + k0 + skch[i] * 8;
      async_copy16(&As[buf][sbase[i]], ga);
      async_copy16(&Bs[buf][sbase[i]], gb);
    }
  };

  auto compute = [&](int buf) {
    bf16x8 af[4], bfr[4];
#pragma unroll
    for (int mt = 0; mt < 4; ++mt) {
      int row = wm + mt * 16 + c;
      int kch = quad ^ ((row >> 1) & 3);
      af[mt] = *(const bf16x8*)&As[buf][(row * 4 + kch) * 8];
    }
#pragma unroll
    for (int nt = 0; nt < 4; ++nt) {
      int rowb = wn + nt * 16 + c;
      int kch = quad ^ ((rowb >> 1) & 3);
      bfr[nt] = *(const bf16x8*)&Bs[buf][(rowb * 4 + kch) * 8];
    }
#pragma unroll
    for (int mt = 0; mt < 4; ++mt)
#pragma unroll
      for (int nt = 0; nt < 4; ++nt)
        acc[mt][nt] = __builtin_amdgcn_mfma_f32_16x16x32_bf16(af[mt], bfr[nt], acc[mt][nt], 0, 0, 0);
  };

  stage(0, 0);
  __syncthreads();
  int cur = 0;
  for (int k0 = TBK; k0 < K; k0 += TBK) {
    stage(cur ^ 1, k0);
    compute(cur);
    __syncthreads();
    cur ^= 1;
  }
  compute(cur);

#pragma unroll
  for (int mt = 0; mt < 4; ++mt)
#pragma unroll
    for (int nt = 0; nt < 4; ++nt)
#pragma unroll
      for (int reg = 0; reg < 4; ++reg) {
        int row = m0 + wm + mt * 16 + quad * 4 + reg;
        int col = n0 + wn + nt * 16 + c;
        C[(size_t)row * N + col] = acc[mt][nt][reg];
      }
}

// ---------------- RoPE ----------------
__global__ void rope_kernel(const float* __restrict__ qkv,
                            bf16_t* __restrict__ qb,
                            bf16_t* __restrict__ kt,
                            bf16_t* __restrict__ vt) {
  const int s = blockIdx.x;
  const float* row = qkv + (size_t)s * QKV_N;
  for (int idx = threadIdx.x; idx < (NHEAD + KVH) * 32; idx += blockDim.x) {
    int h = idx >> 5;
    int i = idx & 31;
    float inv = __expf(-(float)i * (9.210340371976184f / 32.0f));
    float ang = (float)s * inv;
    float c, sn;
    sincosf(ang, &sn, &c);
    if (h < NHEAD) {
      const float* base = row + h * HD;
      float x1 = base[i], x2 = base[i + 32];
      float o1 = (x1 * c - x2 * sn) * 0.125f;
      float o2 = (x2 * c + x1 * sn) * 0.125f;
      bf16_t* q = qb + (size_t)s * H_DIM + h * HD;
      q[i] = (bf16_t)o1;
      q[i + 32] = (bf16_t)o2;
    } else {
      int kh = h - NHEAD;
      const float* base = row + H_DIM + kh * HD;
      float x1 = base[i], x2 = base[i + 32];
      float o1 = x1 * c - x2 * sn;
      float o2 = x2 * c + x1 * sn;
      bf16_t* k = kt + ((size_t)kh * S_LEN + s) * HD;
      k[i] = (bf16_t)o1;
      k[i + 32] = (bf16_t)o2;
    }
  }
  for (int j = threadIdx.x; j < KVH * HD; j += blockDim.x) {
    int kh = j >> 6, d = j & 63;
    vt[((size_t)kh * S_LEN + s) * HD + d] = (bf16_t)row[H_DIM + KVH * HD + kh * HD + d];
  }
}

// ---------------- V transpose: v_t [KVH,S,64] -> v_t2 [KVH,64,S] ----------------
__global__ __launch_bounds__(256) void vtrans_kernel(const bf16_t* __restrict__ vt,
                                                     bf16_t* __restrict__ vt2) {
  __shared__ bf16_t L[64 * 65];
  const int kh = blockIdx.x;
  const int t0 = blockIdx.y * 64;
#pragma unroll
  for (int it = 0; it < 2; ++it) {
    int idx = it * 256 + threadIdx.x;
    int srow = idx >> 3, doff = (idx & 7) * 8;
    bf16x8 v = *(const bf16x8*)(vt + ((size_t)kh * S_LEN + t0 + srow) * HD + doff);
#pragma unroll
    for (int j = 0; j < 8; ++j) L[(doff + j) * 65 + srow] = v[j];
  }
  __syncthreads();
  int d = threadIdx.x >> 2, soff = (threadIdx.x & 3) * 16;
  bf16x8 o0, o1;
#pragma unroll
  for (int j = 0; j < 8; ++j) o0[j] = L[d * 65 + soff + j];
#pragma unroll
  for (int j = 0; j < 8; ++j) o1[j] = L[d * 65 + soff + 8 + j];
  *(bf16x8*)(vt2 + ((size_t)kh * HD + d) * S_LEN + t0 + soff) = o0;
  *(bf16x8*)(vt2 + ((size_t)kh * HD + d) * S_LEN + t0 + soff + 8) = o1;
}

// ---------------- MFMA flash attention (R4) ----------------
// Block (kh, y): qt = 63-y (longest first), q rows [qt*32, qt*32+32), 4 waves = 4 heads.
// 64-key tiles, double-buffered async K/V staging (XOR-swizzled chunks), 1 barrier/tile.
// Ks/Vs rows: 64 elements = 8 chunks of 16B; chunk kc stored at kc^(row&7).
// Scores small (|s|<~5): exp(s-8), l via ones-frag mfma.
#define PSTR 72   // Ps row stride (bf16); 144B = 9*16B

__global__ __launch_bounds__(256) void flash_mfma(const bf16_t* __restrict__ qb,
                                                  const bf16_t* __restrict__ kt,
                                                  const bf16_t* __restrict__ vt2,
                                                  bf16_t* __restrict__ ob) {
  __shared__ __align__(16) bf16_t Ks[2][64 * 64];
  __shared__ __align__(16) bf16_t Vs[2][64 * 64];
  __shared__ __align__(16) bf16_t Ps[4][32 * PSTR];

  const int tid  = threadIdx.x;
  const int lane = tid & 63;
  const int w    = tid >> 6;
  const int kh   = blockIdx.x;
  const int qt   = (int)gridDim.y - 1 - (int)blockIdx.y;   // longest first
  const int s0   = qt * 32;
  const int h    = kh * 4 + w;
  const int c    = lane & 15;
  const int quad = lane >> 4;

  // Q fragments: rows s0+rf*16+c, k(d) = ks*32+quad*8+j
  bf16x8 qf[2][2];
#pragma unroll
  for (int rf = 0; rf < 2; ++rf)
#pragma unroll
    for (int ks = 0; ks < 2; ++ks)
      qf[rf][ks] = *(const bf16x8*)(qb + (size_t)(s0 + rf * 16 + c) * H_DIM + h * HD + ks * 32 + quad * 8);

  bf16x8 onesf;
#pragma unroll
  for (int j = 0; j < 8; ++j) onesf[j] = (bf16_t)1.0f;

  f32x4 acc[2][4] = {};
  f32x4 accl[2]   = {};

  const bf16_t* kbase = kt + (size_t)kh * S_LEN * HD;
  const bf16_t* vbase = vt2 + (size_t)kh * HD * S_LEN;

  // staging geometry: 512 chunks each for K and V; thread handles chunks tid, tid+256
  int srow[2], skc[2], sbase[2];
#pragma unroll
  for (int i = 0; i < 2; ++i) {
    int chunkbase = i * 256 + w * 64;
    int p = chunkbase + lane;
    sbase[i] = chunkbase * 8;
    srow[i]  = p >> 3;
    skc[i]   = (p & 7) ^ (srow[i] & 7);
  }

  auto stage = [&](int buf, int t0) {
#pragma unroll
    for (int i = 0; i < 2; ++i) {
      async_copy16(&Ks[buf][sbase[i]], kbase + (size_t)(t0 + srow[i]) * HD + skc[i] * 8);
      async_copy16(&Vs[buf][sbase[i]], vbase + (size_t)srow[i] * S_LEN + t0 + skc[i] * 8);
    }
  };

  const int ntiles = (qt >> 1) + 1;
  stage(0, 0);
  __syncthreads();
  int buf = 0;

  for (int tile = 0; tile < ntiles; ++tile) {
    const int t0 = tile * 64;
    if (tile + 1 < ntiles) stage(buf ^ 1, (tile + 1) * 64);

    const bool masked = (tile == ntiles - 1);
    const int nact = masked ? (((s0 + 31 - t0) >> 4) + 1) : 4;  // active 16-col groups
    const int nkh  = (nact + 1) >> 1;                           // active 32-key halves

    // QK^T -> exp -> Ps
#pragma unroll
    for (int rf = 0; rf < 2; ++rf) {
      for (int kt2 = 0; kt2 < nact; ++kt2) {
        f32x4 s = {};
#pragma unroll
        for (int ks = 0; ks < 2; ++ks) {
          bf16x8 kf = *(const bf16x8*)&Ks[buf][((kt2 * 16 + c) * 8 + ((ks * 4 + quad) ^ (c & 7))) * 8];
          s = __builtin_amdgcn_mfma_f32_16x16x32_bf16(qf[rf][ks], kf, s, 0, 0, 0);
        }
        const int key = t0 + kt2 * 16 + c;
#pragma unroll
        for (int reg = 0; reg < 4; ++reg) {
          const int row = s0 + rf * 16 + quad * 4 + reg;
          float p = __expf(s[reg] - 8.0f);
          if (masked && key > row) p = 0.f;
          Ps[w][(rf * 16 + quad * 4 + reg) * PSTR + kt2 * 16 + c] = (bf16_t)p;
        }
      }
      // zero-fill inactive cols inside processed k-halves
      for (int kt2 = nact; kt2 < 2 * nkh; ++kt2)
#pragma unroll
        for (int reg = 0; reg < 4; ++reg)
          Ps[w][(rf * 16 + quad * 4 + reg) * PSTR + kt2 * 16 + c] = (bf16_t)0.0f;
    }

    // PV (+ row-sum via ones frag)
    for (int kh2 = 0; kh2 < nkh; ++kh2) {
      bf16x8 vf[4];
#pragma unroll
      for (int dt = 0; dt < 4; ++dt)
        vf[dt] = *(const bf16x8*)&Vs[buf][((dt * 16 + c) * 8 + ((kh2 * 4 + quad) ^ (c & 7))) * 8];
#pragma unroll
      for (int rf = 0; rf < 2; ++rf) {
        bf16x8 pa = *(const bf16x8*)&Ps[w][(rf * 16 + c) * PSTR + kh2 * 32 + quad * 8];
#pragma unroll
        for (int dt = 0; dt < 4; ++dt)
          acc[rf][dt] = __builtin_amdgcn_mfma_f32_16x16x32_bf16(pa, vf[dt], acc[rf][dt], 0, 0, 0);
        accl[rf] = __builtin_amdgcn_mfma_f32_16x16x32_bf16(pa, onesf, accl[rf], 0, 0, 0);
      }
    }

    __syncthreads();   // next buf staged (vmcnt drain) + all waves done with cur buf
    buf ^= 1;
  }

#pragma unroll
  for (int rf = 0; rf < 2; ++rf) {
#pragma unroll
    for (int reg = 0; reg < 4; ++reg) {
      const float inv = 1.0f / accl[rf][reg];
      const int row = s0 + rf * 16 + quad * 4 + reg;
#pragma unroll
      for (int dt = 0; dt < 4; ++dt)
        ob[(size_t)row * H_DIM + h * HD + dt * 16 + c] = (bf16_t)(acc[rf][dt][reg] * inv);
    }
  }
}

// ---------------- launch ----------------
extern "C" void kernel_launch(void* const* d_in, const int* in_sizes, int n_in,
                              void* d_out, int out_size, void* d_ws, size_t ws_size,
                              hipStream_t stream) {
  const float* x     = (const float*)d_in[0];
  const float* w_qkv = (const float*)d_in[1];
  const float* w_o   = (const float*)d_in[2];
  float* out = (float*)d_out;

  char* ws = (char*)d_ws;
  size_t off = 0;
  bf16_t* x_bf    = (bf16_t*)(ws + off); off += (size_t)S_LEN * H_DIM * 2;
  bf16_t* wqkv_bf = (bf16_t*)(ws + off); off += (size_t)QKV_N * H_DIM * 2;
  bf16_t* wo_bf   = (bf16_t*)(ws + off); off += (size_t)H_DIM * H_DIM * 2;
  float*  qkv     = (float*) (ws + off); off += (size_t)S_LEN * QKV_N * 4;
  bf16_t* q_bf    = (bf16_t*)(ws + off); off += (size_t)S_LEN * H_DIM * 2;
  bf16_t* k_t     = (bf16_t*)(ws + off); off += (size_t)KVH * S_LEN * HD * 2;
  bf16_t* v_t     = (bf16_t*)(ws + off); off += (size_t)KVH * S_LEN * HD * 2;
  bf16_t* v_t2    = (bf16_t*)(ws + off); off += (size_t)KVH * S_LEN * HD * 2;
  bf16_t* attn    = (bf16_t*)(ws + off); off += (size_t)S_LEN * H_DIM * 2;

  int n4;
  n4 = S_LEN * H_DIM / 4;
  cast_kernel<<<(n4 + 255) / 256, 256, 0, stream>>>(x, x_bf, n4);
  n4 = QKV_N * H_DIM / 4;
  cast_kernel<<<(n4 + 255) / 256, 256, 0, stream>>>(w_qkv, wqkv_bf, n4);
  n4 = H_DIM * H_DIM / 4;
  cast_kernel<<<(n4 + 255) / 256, 256, 0, stream>>>(w_o, wo_bf, n4);

  gemm128<<<dim3(QKV_N / TBN, S_LEN / TBM), 256, 0, stream>>>(x_bf, wqkv_bf, qkv, S_LEN, QKV_N, H_DIM);

  rope_kernel<<<S_LEN, 256, 0, stream>>>(qkv, q_bf, k_t, v_t);

  vtrans_kernel<<<dim3(KVH, S_LEN / 64), 256, 0, stream>>>(v_t, v_t2);

  flash_mfma<<<dim3(KVH, 64), 256, 0, stream>>>(q_bf, k_t, v_t2, attn);

  gemm128<<<dim3(H_DIM / TBN, S_LEN / TBM), 256, 0, stream>>>(attn, wo_bf, out, S_LEN, H_DIM, H_DIM);
}

// Round 5
// 261.661 us; speedup vs baseline: 1.0310x; 1.0310x over previous
//
#include <hip/hip_runtime.h>

// Attention block: qkv proj -> RoPE -> causal GQA flash attention -> out proj.
// B=1, S=2048, H=2048, NH=32, KVH=8, D=64, G=4.
// R5: split-K flash. exp(s-8) w/o max-sub => partials additive => uniform work
//     chunks (1280 blocks) + fp32 partial buffer + reduce kernel. S^T mfma trick
//     (vectorized P writes), register row-sums, single-buffered K/V (34.8KB LDS
//     -> 4 blocks/CU). Gemm128 unchanged.

typedef __bf16 bf16_t;
typedef __attribute__((ext_vector_type(8))) __bf16 bf16x8;
typedef __attribute__((ext_vector_type(4))) __bf16 bf16x4;
typedef __attribute__((ext_vector_type(4))) float f32x4;

#define S_LEN 2048
#define H_DIM 2048
#define NHEAD 32
#define KVH 8
#define HD 64
#define QKV_N 3072  // (NH + 2*KVH) * D

#define ENT_STRIDE 8320  // floats per partial entry: 4h*32r*64d + 4h*32r l

// ---------------- cast fp32 -> bf16 ----------------
__global__ void cast_kernel(const float* __restrict__ in, bf16_t* __restrict__ out, int n4) {
  int i = blockIdx.x * blockDim.x + threadIdx.x;
  if (i >= n4) return;
  float4 v = ((const float4*)in)[i];
  bf16x4 o;
  o.x = (bf16_t)v.x; o.y = (bf16_t)v.y; o.z = (bf16_t)v.z; o.w = (bf16_t)v.w;
  ((bf16x4*)out)[i] = o;
}

// ---------------- async 16B global -> LDS ----------------
__device__ __forceinline__ void async_copy16(bf16_t* lds_base, const bf16_t* g) {
  __builtin_amdgcn_global_load_lds(
      (const __attribute__((address_space(1))) unsigned int*)g,
      (__attribute__((address_space(3))) unsigned int*)lds_base, 16, 0, 0);
}

// ---------------- GEMM: C[M,N] = A[M,K] * B[N,K]^T (bf16 in, fp32 out) ----------------
#define TBM 128
#define TBN 128
#define TBK 32

__global__ __launch_bounds__(256) void gemm128(const bf16_t* __restrict__ A,
                                               const bf16_t* __restrict__ B,
                                               float* __restrict__ C,
                                               int M, int N, int K) {
  __shared__ __align__(16) bf16_t As[2][TBM * TBK];
  __shared__ __align__(16) bf16_t Bs[2][TBM * TBK];

  const int tid  = threadIdx.x;
  const int lane = tid & 63;
  const int w    = tid >> 6;
  const int wm   = (w >> 1) * 64;
  const int wn   = (w & 1) * 64;
  const int c    = lane & 15;
  const int quad = lane >> 4;
  const int m0   = blockIdx.y * TBM;
  const int n0   = blockIdx.x * TBN;

  f32x4 acc[4][4] = {};

  const bf16_t* Ab = A + (size_t)m0 * K;
  const bf16_t* Bb = B + (size_t)n0 * K;

  int srow[2], skch[2], sbase[2];
#pragma unroll
  for (int i = 0; i < 2; ++i) {
    int chunkbase = i * 256 + w * 64;
    int chunk = chunkbase + lane;
    sbase[i] = chunkbase * 8;
    srow[i]  = chunk >> 2;
    skch[i]  = (chunk & 3) ^ ((chunk >> 3) & 3);
  }

  auto stage = [&](int buf, int k0) {
#pragma unroll
    for (int i = 0; i < 2; ++i) {
      const bf16_t* ga = Ab + (size_t)srow[i] * K + k0 + skch[i] * 8;
      const bf16_t* gb = Bb + (size_t)srow[i] * K + k0 + skch[i] * 8;
      async_copy16(&As[buf][sbase[i]], ga);
      async_copy16(&Bs[buf][sbase[i]], gb);
    }
  };

  auto compute = [&](int buf) {
    bf16x8 af[4], bfr[4];
#pragma unroll
    for (int mt = 0; mt < 4; ++mt) {
      int row = wm + mt * 16 + c;
      int kch = quad ^ ((row >> 1) & 3);
      af[mt] = *(const bf16x8*)&As[buf][(row * 4 + kch) * 8];
    }
#pragma unroll
    for (int nt = 0; nt < 4; ++nt) {
      int rowb = wn + nt * 16 + c;
      int kch = quad ^ ((rowb >> 1) & 3);
      bfr[nt] = *(const bf16x8*)&Bs[buf][(rowb * 4 + kch) * 8];
    }
#pragma unroll
    for (int mt = 0; mt < 4; ++mt)
#pragma unroll
      for (int nt = 0; nt < 4; ++nt)
        acc[mt][nt] = __builtin_amdgcn_mfma_f32_16x16x32_bf16(af[mt], bfr[nt], acc[mt][nt], 0, 0, 0);
  };

  stage(0, 0);
  __syncthreads();
  int cur = 0;
  for (int k0 = TBK; k0 < K; k0 += TBK) {
    stage(cur ^ 1, k0);
    compute(cur);
    __syncthreads();
    cur ^= 1;
  }
  compute(cur);

#pragma unroll
  for (int mt = 0; mt < 4; ++mt)
#pragma unroll
    for (int nt = 0; nt < 4; ++nt)
#pragma unroll
      for (int reg = 0; reg < 4; ++reg) {
        int row = m0 + wm + mt * 16 + quad * 4 + reg;
        int col = n0 + wn + nt * 16 + c;
        C[(size_t)row * N + col] = acc[mt][nt][reg];
      }
}

// ---------------- RoPE ----------------
__global__ void rope_kernel(const float* __restrict__ qkv,
                            bf16_t* __restrict__ qb,
                            bf16_t* __restrict__ kt,
                            bf16_t* __restrict__ vt) {
  const int s = blockIdx.x;
  const float* row = qkv + (size_t)s * QKV_N;
  for (int idx = threadIdx.x; idx < (NHEAD + KVH) * 32; idx += blockDim.x) {
    int h = idx >> 5;
    int i = idx & 31;
    float inv = __expf(-(float)i * (9.210340371976184f / 32.0f));
    float ang = (float)s * inv;
    float c, sn;
    sincosf(ang, &sn, &c);
    if (h < NHEAD) {
      const float* base = row + h * HD;
      float x1 = base[i], x2 = base[i + 32];
      float o1 = (x1 * c - x2 * sn) * 0.125f;
      float o2 = (x2 * c + x1 * sn) * 0.125f;
      bf16_t* q = qb + (size_t)s * H_DIM + h * HD;
      q[i] = (bf16_t)o1;
      q[i + 32] = (bf16_t)o2;
    } else {
      int kh = h - NHEAD;
      const float* base = row + H_DIM + kh * HD;
      float x1 = base[i], x2 = base[i + 32];
      float o1 = x1 * c - x2 * sn;
      float o2 = x2 * c + x1 * sn;
      bf16_t* k = kt + ((size_t)kh * S_LEN + s) * HD;
      k[i] = (bf16_t)o1;
      k[i + 32] = (bf16_t)o2;
    }
  }
  for (int j = threadIdx.x; j < KVH * HD; j += blockDim.x) {
    int kh = j >> 6, d = j & 63;
    vt[((size_t)kh * S_LEN + s) * HD + d] = (bf16_t)row[H_DIM + KVH * HD + kh * HD + d];
  }
}

// ---------------- V transpose: v_t [KVH,S,64] -> v_t2 [KVH,64,S] ----------------
__global__ __launch_bounds__(256) void vtrans_kernel(const bf16_t* __restrict__ vt,
                                                     bf16_t* __restrict__ vt2) {
  __shared__ bf16_t L[64 * 65];
  const int kh = blockIdx.x;
  const int t0 = blockIdx.y * 64;
#pragma unroll
  for (int it = 0; it < 2; ++it) {
    int idx = it * 256 + threadIdx.x;
    int srow = idx >> 3, doff = (idx & 7) * 8;
    bf16x8 v = *(const bf16x8*)(vt + ((size_t)kh * S_LEN + t0 + srow) * HD + doff);
#pragma unroll
    for (int j = 0; j < 8; ++j) L[(doff + j) * 65 + srow] = v[j];
  }
  __syncthreads();
  int d = threadIdx.x >> 2, soff = (threadIdx.x & 3) * 16;
  bf16x8 o0, o1;
#pragma unroll
  for (int j = 0; j < 8; ++j) o0[j] = L[d * 65 + soff + j];
#pragma unroll
  for (int j = 0; j < 8; ++j) o1[j] = L[d * 65 + soff + 8 + j];
  *(bf16x8*)(vt2 + ((size_t)kh * HD + d) * S_LEN + t0 + soff) = o0;
  *(bf16x8*)(vt2 + ((size_t)kh * HD + d) * S_LEN + t0 + soff + 8) = o1;
}

// ---------------- split-K MFMA flash (R5) ----------------
// Work item e in [0,1280): kh = e/160; i = e%160 -> band b (chunks per qt = b+1):
//   i<16: b=0 qt=i          | i<48: b=1 qt=16+(i-16)/2 | i<96: b=2 qt=32+(i-48)/3
//   else: b=3 qt=48+(i-96)/4
// qt covers q rows [qt*32, qt*32+32); T=(qt>>1)+1 64-key tiles split evenly into b+1 chunks.
// Blocks dispatched in descending e (big chunks first). Partials (fp32 Onum + l)
// written to pbuf entry e; flash_reduce sums chunks & normalizes.
#define PSTR 72   // Ps row stride (bf16): 144B, multiple of 16B

__global__ __launch_bounds__(256) void flash_split(const bf16_t* __restrict__ qb,
                                                   const bf16_t* __restrict__ kt,
                                                   const bf16_t* __restrict__ vt2,
                                                   float* __restrict__ pbuf) {
  __shared__ __align__(16) bf16_t Ks[64 * 64];
  __shared__ __align__(16) bf16_t Vs[64 * 64];
  __shared__ __align__(16) bf16_t Ps[4][32 * PSTR];

  const int tid  = threadIdx.x;
  const int lane = tid & 63;
  const int w    = tid >> 6;
  const int e    = (int)gridDim.x - 1 - (int)blockIdx.x;  // big work first
  const int kh   = e / 160;
  const int i    = e - kh * 160;

  int qt, t_begin, t_end;
  {
    int T;
    if (i < 16)      { qt = i;                T = (qt >> 1) + 1; t_begin = 0;                 t_end = T; }
    else if (i < 48) { int r = i - 16; qt = 16 + (r >> 1); int ck = r & 1;
                       T = (qt >> 1) + 1; t_begin = (ck * T) >> 1;      t_end = ((ck + 1) * T) >> 1; }
    else if (i < 96) { int r = i - 48; qt = 32 + r / 3;    int ck = r % 3;
                       T = (qt >> 1) + 1; t_begin = (ck * T) / 3;       t_end = ((ck + 1) * T) / 3; }
    else             { int r = i - 96; qt = 48 + (r >> 2); int ck = r & 3;
                       T = (qt >> 1) + 1; t_begin = (ck * T) >> 2;      t_end = ((ck + 1) * T) >> 2; }
  }
  const int T     = (qt >> 1) + 1;
  const int s0    = qt * 32;
  const int h     = kh * 4 + w;
  const int c     = lane & 15;
  const int quad  = lane >> 4;

  // Q fragments (B operand): B[n=qrow s0+rf*16+c][k=d ks*32+quad*8+j]
  bf16x8 qf[2][2];
#pragma unroll
  for (int rf = 0; rf < 2; ++rf)
#pragma unroll
    for (int ks = 0; ks < 2; ++ks)
      qf[rf][ks] = *(const bf16x8*)(qb + (size_t)(s0 + rf * 16 + c) * H_DIM + h * HD + ks * 32 + quad * 8);

  f32x4 acc[2][4] = {};
  float lsum[2] = {0.f, 0.f};

  const bf16_t* kbase = kt + (size_t)kh * S_LEN * HD;
  const bf16_t* vbase = vt2 + (size_t)kh * HD * S_LEN;

  // staging: 512 16B chunks each for K and V; chunk p at LDS p*16B holds
  // global chunk (row=p>>3, kc=(p&7)^(row&7))
  int srow[2], skc[2], sbase[2];
#pragma unroll
  for (int i2 = 0; i2 < 2; ++i2) {
    int chunkbase = i2 * 256 + w * 64;
    int p = chunkbase + lane;
    sbase[i2] = chunkbase * 8;
    srow[i2]  = p >> 3;
    skc[i2]   = (p & 7) ^ (srow[i2] & 7);
  }

  for (int tile = t_begin; tile < t_end; ++tile) {
    const int t0 = tile * 64;
    __syncthreads();  // everyone done reading previous tile's Ks/Vs
#pragma unroll
    for (int i2 = 0; i2 < 2; ++i2) {
      async_copy16(&Ks[sbase[i2]], kbase + (size_t)(t0 + srow[i2]) * HD + skc[i2] * 8);
      async_copy16(&Vs[sbase[i2]], vbase + (size_t)srow[i2] * S_LEN + t0 + skc[i2] * 8);
    }
    __syncthreads();  // vmcnt drained: tile staged

    const bool masked = (tile == T - 1);
    int nact = 4;
    if (masked) { nact = ((s0 + 31 - t0) >> 4) + 1; if (nact > 4) nact = 4; }
    const int nkh = (nact + 1) >> 1;

    // S^T = mfma(A=K, B=Q): D[m=key_local=quad*4+reg][n=qrow=c]
#pragma unroll
    for (int rf = 0; rf < 2; ++rf) {
      for (int kt2 = 0; kt2 < nact; ++kt2) {
        f32x4 st = {};
#pragma unroll
        for (int ks = 0; ks < 2; ++ks) {
          bf16x8 kf = *(const bf16x8*)&Ks[((kt2 * 16 + c) * 8 + ((ks * 4 + quad) ^ (c & 7))) * 8];
          st = __builtin_amdgcn_mfma_f32_16x16x32_bf16(kf, qf[rf][ks], st, 0, 0, 0);
        }
        const int row = s0 + rf * 16 + c;
        bf16x4 pk;
#pragma unroll
        for (int reg = 0; reg < 4; ++reg) {
          const int key = t0 + kt2 * 16 + quad * 4 + reg;
          float p = __expf(st[reg] - 8.0f);
          if (masked && key > row) p = 0.f;
          pk[reg] = (bf16_t)p;
          lsum[rf] += p;
        }
        *(bf16x4*)&Ps[w][(rf * 16 + c) * PSTR + kt2 * 16 + quad * 4] = pk;
      }
      // zero-fill cols of partially-active 32-key halves
      for (int kt2 = nact; kt2 < 2 * nkh; ++kt2) {
        bf16x4 z = {};
        *(bf16x4*)&Ps[w][(rf * 16 + c) * PSTR + kt2 * 16 + quad * 4] = z;
      }
    }

    // PV: A = P[m=qrow][k=key], B = V^T[n=d][k=key]
    for (int kh2 = 0; kh2 < nkh; ++kh2) {
      bf16x8 vf[4];
#pragma unroll
      for (int dt = 0; dt < 4; ++dt)
        vf[dt] = *(const bf16x8*)&Vs[((dt * 16 + c) * 8 + ((kh2 * 4 + quad) ^ (c & 7))) * 8];
#pragma unroll
      for (int rf = 0; rf < 2; ++rf) {
        bf16x8 pa = *(const bf16x8*)&Ps[w][(rf * 16 + c) * PSTR + kh2 * 32 + quad * 8];
#pragma unroll
        for (int dt = 0; dt < 4; ++dt)
          acc[rf][dt] = __builtin_amdgcn_mfma_f32_16x16x32_bf16(pa, vf[dt], acc[rf][dt], 0, 0, 0);
      }
    }
  }

  // cross-quad reduce of lsum (lanes c, c+16, c+32, c+48 hold partial key-sums)
#pragma unroll
  for (int rf = 0; rf < 2; ++rf) {
    lsum[rf] += __shfl_xor(lsum[rf], 16);
    lsum[rf] += __shfl_xor(lsum[rf], 32);
  }

  // write partials: entry e
  float* ent = pbuf + (size_t)e * ENT_STRIDE;
#pragma unroll
  for (int rf = 0; rf < 2; ++rf) {
#pragma unroll
    for (int dt = 0; dt < 4; ++dt)
#pragma unroll
      for (int reg = 0; reg < 4; ++reg)
        ent[w * 2048 + (rf * 16 + quad * 4 + reg) * 64 + dt * 16 + c] = acc[rf][dt][reg];
    ent[8192 + w * 32 + rf * 16 + c] = lsum[rf];  // quads write dup same value
  }
}

// ---------------- reduce: sum chunks, normalize, write bf16 attn ----------------
__global__ __launch_bounds__(256) void flash_reduce(const float* __restrict__ pbuf,
                                                    bf16_t* __restrict__ attn) {
  const int kh = blockIdx.x >> 6;
  const int qt = blockIdx.x & 63;
  const int b  = qt >> 4;
  int base;
  if (b == 0)      base = kh * 160 + qt;
  else if (b == 1) base = kh * 160 + 16 + (qt - 16) * 2;
  else if (b == 2) base = kh * 160 + 48 + (qt - 32) * 3;
  else             base = kh * 160 + 96 + (qt - 48) * 4;
  const int nch = b + 1;

  const int t   = threadIdx.x;
  const int h2  = t >> 6;
  const int row = (t >> 1) & 31;
  const int dh  = t & 1;

  f32x4 o[8] = {};
  float l = 0.f;
  for (int ci = 0; ci < nch; ++ci) {
    const float* ent = pbuf + (size_t)(base + ci) * ENT_STRIDE;
    const float* p = ent + h2 * 2048 + row * 64 + dh * 32;
#pragma unroll
    for (int j = 0; j < 8; ++j) {
      f32x4 v = ((const f32x4*)p)[j];
      o[j][0] += v[0]; o[j][1] += v[1]; o[j][2] += v[2]; o[j][3] += v[3];
    }
    l += ent[8192 + h2 * 32 + row];
  }
  const float inv = 1.0f / l;
  bf16_t* dst = attn + (size_t)(qt * 32 + row) * H_DIM + (kh * 4 + h2) * 64 + dh * 32;
#pragma unroll
  for (int j = 0; j < 8; ++j) {
    bf16x4 ov;
    ov[0] = (bf16_t)(o[j][0] * inv); ov[1] = (bf16_t)(o[j][1] * inv);
    ov[2] = (bf16_t)(o[j][2] * inv); ov[3] = (bf16_t)(o[j][3] * inv);
    *(bf16x4*)(dst + j * 4) = ov;
  }
}

// ---------------- launch ----------------
extern "C" void kernel_launch(void* const* d_in, const int* in_sizes, int n_in,
                              void* d_out, int out_size, void* d_ws, size_t ws_size,
                              hipStream_t stream) {
  const float* x     = (const float*)d_in[0];
  const float* w_qkv = (const float*)d_in[1];
  const float* w_o   = (const float*)d_in[2];
  float* out = (float*)d_out;

  char* ws = (char*)d_ws;
  // Region A (overlaid): cast/gemm1/rope stage vs flash partials (dead by flash time)
  size_t off = 0;
  bf16_t* x_bf    = (bf16_t*)(ws + off); off += (size_t)S_LEN * H_DIM * 2;    //  8.39 MB
  bf16_t* wqkv_bf = (bf16_t*)(ws + off); off += (size_t)QKV_N * H_DIM * 2;    // 12.58 MB
  float*  qkv     = (float*) (ws + off); off += (size_t)S_LEN * QKV_N * 4;    // 25.17 MB
  // pbuf overlays region A: 1280 * 8320 * 4 = 42.6 MB <= 46.1 MB
  float*  pbuf    = (float*)ws;
  bf16_t* wo_bf   = (bf16_t*)(ws + off); off += (size_t)H_DIM * H_DIM * 2;
  bf16_t* q_bf    = (bf16_t*)(ws + off); off += (size_t)S_LEN * H_DIM * 2;
  bf16_t* k_t     = (bf16_t*)(ws + off); off += (size_t)KVH * S_LEN * HD * 2;
  bf16_t* v_t     = (bf16_t*)(ws + off); off += (size_t)KVH * S_LEN * HD * 2;
  bf16_t* v_t2    = (bf16_t*)(ws + off); off += (size_t)KVH * S_LEN * HD * 2;
  bf16_t* attn    = (bf16_t*)(ws + off); off += (size_t)S_LEN * H_DIM * 2;

  int n4;
  n4 = S_LEN * H_DIM / 4;
  cast_kernel<<<(n4 + 255) / 256, 256, 0, stream>>>(x, x_bf, n4);
  n4 = QKV_N * H_DIM / 4;
  cast_kernel<<<(n4 + 255) / 256, 256, 0, stream>>>(w_qkv, wqkv_bf, n4);
  n4 = H_DIM * H_DIM / 4;
  cast_kernel<<<(n4 + 255) / 256, 256, 0, stream>>>(w_o, wo_bf, n4);

  gemm128<<<dim3(QKV_N / TBN, S_LEN / TBM), 256, 0, stream>>>(x_bf, wqkv_bf, qkv, S_LEN, QKV_N, H_DIM);

  rope_kernel<<<S_LEN, 256, 0, stream>>>(qkv, q_bf, k_t, v_t);

  vtrans_kernel<<<dim3(KVH, S_LEN / 64), 256, 0, stream>>>(v_t, v_t2);

  flash_split<<<1280, 256, 0, stream>>>(q_bf, k_t, v_t2, pbuf);
  flash_reduce<<<512, 256, 0, stream>>>(pbuf, attn);

  gemm128<<<dim3(H_DIM / TBN, S_LEN / TBM), 256, 0, stream>>>(attn, wo_bf, out, S_LEN, H_DIM, H_DIM);
}

// Round 6
// 246.832 us; speedup vs baseline: 1.0930x; 1.0601x over previous
//
#include <hip/hip_runtime.h>

// Attention block: qkv proj -> RoPE -> causal GQA flash attention -> out proj.
// B=1, S=2048, H=2048, NH=32, KVH=8, D=64, G=4.
// R6: gemm K-loop restructured: triple-buffered LDS, raw s_barrier + partial
//     s_waitcnt vmcnt(4) (prefetch distance 2, no full drain at barrier).
//     Fused cast kernel; flash band-0 writes attn directly; smaller reduce.

typedef __bf16 bf16_t;
typedef __attribute__((ext_vector_type(8))) __bf16 bf16x8;
typedef __attribute__((ext_vector_type(4))) __bf16 bf16x4;
typedef __attribute__((ext_vector_type(4))) float f32x4;

#define S_LEN 2048
#define H_DIM 2048
#define NHEAD 32
#define KVH 8
#define HD 64
#define QKV_N 3072  // (NH + 2*KVH) * D

#define ENT_STRIDE 8320  // floats per partial entry: 4h*32r*64d + 4h*32r l

// ---------------- fused cast fp32 -> bf16 (x, w_qkv, w_o) ----------------
__global__ void cast3_kernel(const float* __restrict__ x, const float* __restrict__ wq,
                             const float* __restrict__ wo, bf16_t* __restrict__ xb,
                             bf16_t* __restrict__ wqb, bf16_t* __restrict__ wob) {
  int i = blockIdx.x * blockDim.x + threadIdx.x;
  const int n1 = S_LEN * H_DIM / 4, n2 = QKV_N * H_DIM / 4, n3 = H_DIM * H_DIM / 4;
  const float* src; bf16_t* dst; int j;
  if (i < n1)           { src = x;  dst = xb;  j = i; }
  else if (i < n1 + n2) { src = wq; dst = wqb; j = i - n1; }
  else if (i < n1 + n2 + n3) { src = wo; dst = wob; j = i - n1 - n2; }
  else return;
  float4 v = ((const float4*)src)[j];
  bf16x4 o;
  o.x = (bf16_t)v.x; o.y = (bf16_t)v.y; o.z = (bf16_t)v.z; o.w = (bf16_t)v.w;
  ((bf16x4*)dst)[j] = o;
}

// ---------------- async 16B global -> LDS ----------------
__device__ __forceinline__ void async_copy16(bf16_t* lds_base, const bf16_t* g) {
  __builtin_amdgcn_global_load_lds(
      (const __attribute__((address_space(1))) unsigned int*)g,
      (__attribute__((address_space(3))) unsigned int*)lds_base, 16, 0, 0);
}

// ---------------- GEMM: C[M,N] = A[M,K] * B[N,K]^T (bf16 in, fp32 out) ----------------
// 128x128 tile, 4 waves. Triple-buffered staging, prefetch distance 2.
// Per stage: 4 global_load_lds per wave -> vmcnt(4) = "oldest staged tile landed".
#define TBM 128
#define TBN 128
#define TBK 32

__global__ __launch_bounds__(256) void gemm128(const bf16_t* __restrict__ A,
                                               const bf16_t* __restrict__ B,
                                               float* __restrict__ C,
                                               int M, int N, int K) {
  __shared__ __align__(16) bf16_t As[3][TBM * TBK];
  __shared__ __align__(16) bf16_t Bs[3][TBM * TBK];

  const int tid  = threadIdx.x;
  const int lane = tid & 63;
  const int w    = tid >> 6;
  const int wm   = (w >> 1) * 64;
  const int wn   = (w & 1) * 64;
  const int c    = lane & 15;
  const int quad = lane >> 4;
  const int m0   = blockIdx.y * TBM;
  const int n0   = blockIdx.x * TBN;

  f32x4 acc[4][4] = {};

  const bf16_t* Ab = A + (size_t)m0 * K;
  const bf16_t* Bb = B + (size_t)n0 * K;

  int srow[2], skch[2], sbase[2];
#pragma unroll
  for (int i = 0; i < 2; ++i) {
    int chunkbase = i * 256 + w * 64;
    int chunk = chunkbase + lane;
    sbase[i] = chunkbase * 8;
    srow[i]  = chunk >> 2;
    skch[i]  = (chunk & 3) ^ ((chunk >> 3) & 3);
  }

  auto stage = [&](int buf, int k0) {
#pragma unroll
    for (int i = 0; i < 2; ++i) {
      const bf16_t* ga = Ab + (size_t)srow[i] * K + k0 + skch[i] * 8;
      const bf16_t* gb = Bb + (size_t)srow[i] * K + k0 + skch[i] * 8;
      async_copy16(&As[buf][sbase[i]], ga);
      async_copy16(&Bs[buf][sbase[i]], gb);
    }
  };

  auto compute = [&](int buf) {
    bf16x8 af[4], bfr[4];
#pragma unroll
    for (int mt = 0; mt < 4; ++mt) {
      int row = wm + mt * 16 + c;
      int kch = quad ^ ((row >> 1) & 3);
      af[mt] = *(const bf16x8*)&As[buf][(row * 4 + kch) * 8];
    }
#pragma unroll
    for (int nt = 0; nt < 4; ++nt) {
      int rowb = wn + nt * 16 + c;
      int kch = quad ^ ((rowb >> 1) & 3);
      bfr[nt] = *(const bf16x8*)&Bs[buf][(rowb * 4 + kch) * 8];
    }
#pragma unroll
    for (int mt = 0; mt < 4; ++mt)
#pragma unroll
      for (int nt = 0; nt < 4; ++nt)
        acc[mt][nt] = __builtin_amdgcn_mfma_f32_16x16x32_bf16(af[mt], bfr[nt], acc[mt][nt], 0, 0, 0);
  };

  const int NS = K / TBK;
  stage(0, 0);
  stage(1, TBK);
  int sc = 0, sp = 2;   // compute slot, prefetch slot
  for (int k = 0; k < NS; ++k) {
    if (k + 1 < NS) {
      asm volatile("s_waitcnt vmcnt(4)" ::: "memory");   // oldest tile landed; newest 4 stay in flight
    } else {
      asm volatile("s_waitcnt vmcnt(0)" ::: "memory");   // last tile: nothing newer
    }
    __builtin_amdgcn_s_barrier();                        // raw barrier: no implicit drain
    if (k + 2 < NS) stage(sp, (k + 2) * TBK);
    compute(sc);
    sc = (sc == 2) ? 0 : sc + 1;
    sp = (sp == 2) ? 0 : sp + 1;
  }

#pragma unroll
  for (int mt = 0; mt < 4; ++mt)
#pragma unroll
    for (int nt = 0; nt < 4; ++nt)
#pragma unroll
      for (int reg = 0; reg < 4; ++reg) {
        int row = m0 + wm + mt * 16 + quad * 4 + reg;
        int col = n0 + wn + nt * 16 + c;
        C[(size_t)row * N + col] = acc[mt][nt][reg];
      }
}

// ---------------- RoPE ----------------
__global__ void rope_kernel(const float* __restrict__ qkv,
                            bf16_t* __restrict__ qb,
                            bf16_t* __restrict__ kt,
                            bf16_t* __restrict__ vt) {
  const int s = blockIdx.x;
  const float* row = qkv + (size_t)s * QKV_N;
  for (int idx = threadIdx.x; idx < (NHEAD + KVH) * 32; idx += blockDim.x) {
    int h = idx >> 5;
    int i = idx & 31;
    float inv = __expf(-(float)i * (9.210340371976184f / 32.0f));
    float ang = (float)s * inv;
    float c, sn;
    __sincosf(ang, &sn, &c);
    if (h < NHEAD) {
      const float* base = row + h * HD;
      float x1 = base[i], x2 = base[i + 32];
      float o1 = (x1 * c - x2 * sn) * 0.125f;
      float o2 = (x2 * c + x1 * sn) * 0.125f;
      bf16_t* q = qb + (size_t)s * H_DIM + h * HD;
      q[i] = (bf16_t)o1;
      q[i + 32] = (bf16_t)o2;
    } else {
      int kh = h - NHEAD;
      const float* base = row + H_DIM + kh * HD;
      float x1 = base[i], x2 = base[i + 32];
      float o1 = x1 * c - x2 * sn;
      float o2 = x2 * c + x1 * sn;
      bf16_t* k = kt + ((size_t)kh * S_LEN + s) * HD;
      k[i] = (bf16_t)o1;
      k[i + 32] = (bf16_t)o2;
    }
  }
  for (int j = threadIdx.x; j < KVH * HD; j += blockDim.x) {
    int kh = j >> 6, d = j & 63;
    vt[((size_t)kh * S_LEN + s) * HD + d] = (bf16_t)row[H_DIM + KVH * HD + kh * HD + d];
  }
}

// ---------------- V transpose: v_t [KVH,S,64] -> v_t2 [KVH,64,S] ----------------
__global__ __launch_bounds__(256) void vtrans_kernel(const bf16_t* __restrict__ vt,
                                                     bf16_t* __restrict__ vt2) {
  __shared__ bf16_t L[64 * 65];
  const int kh = blockIdx.x;
  const int t0 = blockIdx.y * 64;
#pragma unroll
  for (int it = 0; it < 2; ++it) {
    int idx = it * 256 + threadIdx.x;
    int srow = idx >> 3, doff = (idx & 7) * 8;
    bf16x8 v = *(const bf16x8*)(vt + ((size_t)kh * S_LEN + t0 + srow) * HD + doff);
#pragma unroll
    for (int j = 0; j < 8; ++j) L[(doff + j) * 65 + srow] = v[j];
  }
  __syncthreads();
  int d = threadIdx.x >> 2, soff = (threadIdx.x & 3) * 16;
  bf16x8 o0, o1;
#pragma unroll
  for (int j = 0; j < 8; ++j) o0[j] = L[d * 65 + soff + j];
#pragma unroll
  for (int j = 0; j < 8; ++j) o1[j] = L[d * 65 + soff + 8 + j];
  *(bf16x8*)(vt2 + ((size_t)kh * HD + d) * S_LEN + t0 + soff) = o0;
  *(bf16x8*)(vt2 + ((size_t)kh * HD + d) * S_LEN + t0 + soff + 8) = o1;
}

// ---------------- split-K MFMA flash ----------------
// Work item e in [0,1280): kh=e/160; i=e%160 -> band b (chunks per qt = b+1).
// Band 0 (i<16, single chunk): normalize and write attn directly (skip pbuf).
#define PSTR 72

__global__ __launch_bounds__(256) void flash_split(const bf16_t* __restrict__ qb,
                                                   const bf16_t* __restrict__ kt,
                                                   const bf16_t* __restrict__ vt2,
                                                   float* __restrict__ pbuf,
                                                   bf16_t* __restrict__ attn) {
  __shared__ __align__(16) bf16_t Ks[64 * 64];
  __shared__ __align__(16) bf16_t Vs[64 * 64];
  __shared__ __align__(16) bf16_t Ps[4][32 * PSTR];

  const int tid  = threadIdx.x;
  const int lane = tid & 63;
  const int w    = tid >> 6;
  const int e    = (int)gridDim.x - 1 - (int)blockIdx.x;  // big work first
  const int kh   = e / 160;
  const int i    = e - kh * 160;

  int qt, t_begin, t_end;
  {
    int T;
    if (i < 16)      { qt = i;                T = (qt >> 1) + 1; t_begin = 0;                 t_end = T; }
    else if (i < 48) { int r = i - 16; qt = 16 + (r >> 1); int ck = r & 1;
                       T = (qt >> 1) + 1; t_begin = (ck * T) >> 1;      t_end = ((ck + 1) * T) >> 1; }
    else if (i < 96) { int r = i - 48; qt = 32 + r / 3;    int ck = r % 3;
                       T = (qt >> 1) + 1; t_begin = (ck * T) / 3;       t_end = ((ck + 1) * T) / 3; }
    else             { int r = i - 96; qt = 48 + (r >> 2); int ck = r & 3;
                       T = (qt >> 1) + 1; t_begin = (ck * T) >> 2;      t_end = ((ck + 1) * T) >> 2; }
  }
  const int T     = (qt >> 1) + 1;
  const int s0    = qt * 32;
  const int h     = kh * 4 + w;
  const int c     = lane & 15;
  const int quad  = lane >> 4;

  bf16x8 qf[2][2];
#pragma unroll
  for (int rf = 0; rf < 2; ++rf)
#pragma unroll
    for (int ks = 0; ks < 2; ++ks)
      qf[rf][ks] = *(const bf16x8*)(qb + (size_t)(s0 + rf * 16 + c) * H_DIM + h * HD + ks * 32 + quad * 8);

  f32x4 acc[2][4] = {};
  float lsum[2] = {0.f, 0.f};

  const bf16_t* kbase = kt + (size_t)kh * S_LEN * HD;
  const bf16_t* vbase = vt2 + (size_t)kh * HD * S_LEN;

  int srow[2], skc[2], sbase[2];
#pragma unroll
  for (int i2 = 0; i2 < 2; ++i2) {
    int chunkbase = i2 * 256 + w * 64;
    int p = chunkbase + lane;
    sbase[i2] = chunkbase * 8;
    srow[i2]  = p >> 3;
    skc[i2]   = (p & 7) ^ (srow[i2] & 7);
  }

  for (int tile = t_begin; tile < t_end; ++tile) {
    const int t0 = tile * 64;
    __syncthreads();
#pragma unroll
    for (int i2 = 0; i2 < 2; ++i2) {
      async_copy16(&Ks[sbase[i2]], kbase + (size_t)(t0 + srow[i2]) * HD + skc[i2] * 8);
      async_copy16(&Vs[sbase[i2]], vbase + (size_t)srow[i2] * S_LEN + t0 + skc[i2] * 8);
    }
    __syncthreads();

    const bool masked = (tile == T - 1);
    int nact = 4;
    if (masked) { nact = ((s0 + 31 - t0) >> 4) + 1; if (nact > 4) nact = 4; }
    const int nkh = (nact + 1) >> 1;

#pragma unroll
    for (int rf = 0; rf < 2; ++rf) {
      for (int kt2 = 0; kt2 < nact; ++kt2) {
        f32x4 st = {};
#pragma unroll
        for (int ks = 0; ks < 2; ++ks) {
          bf16x8 kf = *(const bf16x8*)&Ks[((kt2 * 16 + c) * 8 + ((ks * 4 + quad) ^ (c & 7))) * 8];
          st = __builtin_amdgcn_mfma_f32_16x16x32_bf16(kf, qf[rf][ks], st, 0, 0, 0);
        }
        const int row = s0 + rf * 16 + c;
        bf16x4 pk;
#pragma unroll
        for (int reg = 0; reg < 4; ++reg) {
          const int key = t0 + kt2 * 16 + quad * 4 + reg;
          float p = __expf(st[reg] - 8.0f);
          if (masked && key > row) p = 0.f;
          pk[reg] = (bf16_t)p;
          lsum[rf] += p;
        }
        *(bf16x4*)&Ps[w][(rf * 16 + c) * PSTR + kt2 * 16 + quad * 4] = pk;
      }
      for (int kt2 = nact; kt2 < 2 * nkh; ++kt2) {
        bf16x4 z = {};
        *(bf16x4*)&Ps[w][(rf * 16 + c) * PSTR + kt2 * 16 + quad * 4] = z;
      }
    }

    for (int kh2 = 0; kh2 < nkh; ++kh2) {
      bf16x8 vf[4];
#pragma unroll
      for (int dt = 0; dt < 4; ++dt)
        vf[dt] = *(const bf16x8*)&Vs[((dt * 16 + c) * 8 + ((kh2 * 4 + quad) ^ (c & 7))) * 8];
#pragma unroll
      for (int rf = 0; rf < 2; ++rf) {
        bf16x8 pa = *(const bf16x8*)&Ps[w][(rf * 16 + c) * PSTR + kh2 * 32 + quad * 8];
#pragma unroll
        for (int dt = 0; dt < 4; ++dt)
          acc[rf][dt] = __builtin_amdgcn_mfma_f32_16x16x32_bf16(pa, vf[dt], acc[rf][dt], 0, 0, 0);
      }
    }
  }

  // cross-quad reduce of lsum (lanes c, c+16, c+32, c+48 hold partial key-sums)
#pragma unroll
  for (int rf = 0; rf < 2; ++rf) {
    lsum[rf] += __shfl_xor(lsum[rf], 16);
    lsum[rf] += __shfl_xor(lsum[rf], 32);
  }

  if (i < 16) {
    // single-chunk entry: normalize and write attn directly.
    // lsum is indexed by row=c; acc rows are quad*4+reg -> exchange via wave-sync LDS.
    float* lbuf = (float*)&Ps[w][0];
#pragma unroll
    for (int rf = 0; rf < 2; ++rf) lbuf[rf * 16 + c] = lsum[rf];
    asm volatile("s_waitcnt lgkmcnt(0)" ::: "memory");
#pragma unroll
    for (int rf = 0; rf < 2; ++rf)
#pragma unroll
      for (int reg = 0; reg < 4; ++reg) {
        const float inv = 1.0f / lbuf[rf * 16 + quad * 4 + reg];
        const int row = s0 + rf * 16 + quad * 4 + reg;
#pragma unroll
        for (int dt = 0; dt < 4; ++dt)
          attn[(size_t)row * H_DIM + h * HD + dt * 16 + c] = (bf16_t)(acc[rf][dt][reg] * inv);
      }
  } else {
    float* ent = pbuf + (size_t)e * ENT_STRIDE;
#pragma unroll
    for (int rf = 0; rf < 2; ++rf) {
#pragma unroll
      for (int dt = 0; dt < 4; ++dt)
#pragma unroll
        for (int reg = 0; reg < 4; ++reg)
          ent[w * 2048 + (rf * 16 + quad * 4 + reg) * 64 + dt * 16 + c] = acc[rf][dt][reg];
      ent[8192 + w * 32 + rf * 16 + c] = lsum[rf];
    }
  }
}

// ---------------- reduce: sum chunks (qt>=16), normalize, write bf16 attn ----------------
__global__ __launch_bounds__(256) void flash_reduce(const float* __restrict__ pbuf,
                                                    bf16_t* __restrict__ attn) {
  const int kh = blockIdx.x / 48;
  const int qt = 16 + (blockIdx.x % 48);
  const int b  = qt >> 4;
  int base;
  if (b == 1)      base = kh * 160 + 16 + (qt - 16) * 2;
  else if (b == 2) base = kh * 160 + 48 + (qt - 32) * 3;
  else             base = kh * 160 + 96 + (qt - 48) * 4;
  const int nch = b + 1;

  const int t   = threadIdx.x;
  const int h2  = t >> 6;
  const int row = (t >> 1) & 31;
  const int dh  = t & 1;

  f32x4 o[8] = {};
  float l = 0.f;
  for (int ci = 0; ci < nch; ++ci) {
    const float* ent = pbuf + (size_t)(base + ci) * ENT_STRIDE;
    const float* p = ent + h2 * 2048 + row * 64 + dh * 32;
#pragma unroll
    for (int j = 0; j < 8; ++j) {
      f32x4 v = ((const f32x4*)p)[j];
      o[j][0] += v[0]; o[j][1] += v[1]; o[j][2] += v[2]; o[j][3] += v[3];
    }
    l += ent[8192 + h2 * 32 + row];
  }
  const float inv = 1.0f / l;
  bf16_t* dst = attn + (size_t)(qt * 32 + row) * H_DIM + (kh * 4 + h2) * 64 + dh * 32;
#pragma unroll
  for (int j = 0; j < 8; ++j) {
    bf16x4 ov;
    ov[0] = (bf16_t)(o[j][0] * inv); ov[1] = (bf16_t)(o[j][1] * inv);
    ov[2] = (bf16_t)(o[j][2] * inv); ov[3] = (bf16_t)(o[j][3] * inv);
    *(bf16x4*)(dst + j * 4) = ov;
  }
}

// ---------------- launch ----------------
extern "C" void kernel_launch(void* const* d_in, const int* in_sizes, int n_in,
                              void* d_out, int out_size, void* d_ws, size_t ws_size,
                              hipStream_t stream) {
  const float* x     = (const float*)d_in[0];
  const float* w_qkv = (const float*)d_in[1];
  const float* w_o   = (const float*)d_in[2];
  float* out = (float*)d_out;

  char* ws = (char*)d_ws;
  size_t off = 0;
  bf16_t* x_bf    = (bf16_t*)(ws + off); off += (size_t)S_LEN * H_DIM * 2;    //  8.39 MB
  bf16_t* wqkv_bf = (bf16_t*)(ws + off); off += (size_t)QKV_N * H_DIM * 2;    // 12.58 MB
  float*  qkv     = (float*) (ws + off); off += (size_t)S_LEN * QKV_N * 4;    // 25.17 MB
  // pbuf overlays the above (dead by flash time): 1280 * 8320 * 4 = 42.6 MB <= 46.1 MB
  float*  pbuf    = (float*)ws;
  bf16_t* wo_bf   = (bf16_t*)(ws + off); off += (size_t)H_DIM * H_DIM * 2;
  bf16_t* q_bf    = (bf16_t*)(ws + off); off += (size_t)S_LEN * H_DIM * 2;
  bf16_t* k_t     = (bf16_t*)(ws + off); off += (size_t)KVH * S_LEN * HD * 2;
  bf16_t* v_t     = (bf16_t*)(ws + off); off += (size_t)KVH * S_LEN * HD * 2;
  bf16_t* v_t2    = (bf16_t*)(ws + off); off += (size_t)KVH * S_LEN * HD * 2;
  bf16_t* attn    = (bf16_t*)(ws + off); off += (size_t)S_LEN * H_DIM * 2;

  const int ntot = (S_LEN * H_DIM + QKV_N * H_DIM + H_DIM * H_DIM) / 4;
  cast3_kernel<<<(ntot + 255) / 256, 256, 0, stream>>>(x, w_qkv, w_o, x_bf, wqkv_bf, wo_bf);

  gemm128<<<dim3(QKV_N / TBN, S_LEN / TBM), 256, 0, stream>>>(x_bf, wqkv_bf, qkv, S_LEN, QKV_N, H_DIM);

  rope_kernel<<<S_LEN, 256, 0, stream>>>(qkv, q_bf, k_t, v_t);

  vtrans_kernel<<<dim3(KVH, S_LEN / 64), 256, 0, stream>>>(v_t, v_t2);

  flash_split<<<1280, 256, 0, stream>>>(q_bf, k_t, v_t2, pbuf, attn);
  flash_reduce<<<384, 256, 0, stream>>>(pbuf, attn);

  gemm128<<<dim3(H_DIM / TBN, S_LEN / TBM), 256, 0, stream>>>(attn, wo_bf, out, S_LEN, H_DIM, H_DIM);
}

// Round 7
// 233.277 us; speedup vs baseline: 1.1565x; 1.0581x over previous
//
#include <hip/hip_runtime.h>

// Attention block: qkv proj -> RoPE -> causal GQA flash attention -> out proj.
// B=1, S=2048, H=2048, NH=32, KVH=8, D=64, G=4.
// R7: 512-thread gemm blocks (8 waves -> 12 waves/CU latency hiding), RoPE +
//     V-transpose fused into qkv-gemm epilogue (rope/vtrans kernels and the
//     fp32 qkv buffer eliminated). Flash split-K unchanged.

typedef __bf16 bf16_t;
typedef __attribute__((ext_vector_type(8))) __bf16 bf16x8;
typedef __attribute__((ext_vector_type(4))) __bf16 bf16x4;
typedef __attribute__((ext_vector_type(4))) float f32x4;

#define S_LEN 2048
#define H_DIM 2048
#define NHEAD 32
#define KVH 8
#define HD 64
#define QKV_N 3072  // (NH + 2*KVH) * D

#define ENT_STRIDE 8320  // floats per partial entry: 4h*32r*64d + 4h*32r l

// ---------------- fused cast fp32 -> bf16 (x, w_qkv, w_o) ----------------
__global__ void cast3_kernel(const float* __restrict__ x, const float* __restrict__ wq,
                             const float* __restrict__ wo, bf16_t* __restrict__ xb,
                             bf16_t* __restrict__ wqb, bf16_t* __restrict__ wob) {
  int i = blockIdx.x * blockDim.x + threadIdx.x;
  const int n1 = S_LEN * H_DIM / 4, n2 = QKV_N * H_DIM / 4, n3 = H_DIM * H_DIM / 4;
  const float* src; bf16_t* dst; int j;
  if (i < n1)           { src = x;  dst = xb;  j = i; }
  else if (i < n1 + n2) { src = wq; dst = wqb; j = i - n1; }
  else if (i < n1 + n2 + n3) { src = wo; dst = wob; j = i - n1 - n2; }
  else return;
  float4 v = ((const float4*)src)[j];
  bf16x4 o;
  o.x = (bf16_t)v.x; o.y = (bf16_t)v.y; o.z = (bf16_t)v.z; o.w = (bf16_t)v.w;
  ((bf16x4*)dst)[j] = o;
}

// ---------------- async 16B global -> LDS ----------------
__device__ __forceinline__ void async_copy16(bf16_t* lds_base, const bf16_t* g) {
  __builtin_amdgcn_global_load_lds(
      (const __attribute__((address_space(1))) unsigned int*)g,
      (__attribute__((address_space(3))) unsigned int*)lds_base, 16, 0, 0);
}

// ---------------- GEMM: C[M,N] = A[M,K] * B[N,K]^T (bf16 in) ----------------
// 128x128 tile, 512 threads = 8 waves in 4x2 (wave tile 32 rows x 64 cols).
// Triple-buffered async staging, prefetch distance 2, raw s_barrier + vmcnt(2).
// EPI=0: C fp32 plain.  EPI=1: fused qkv epilogue (RoPE q/k, V transpose).
#define GBM 128
#define GBN 128
#define GBK 32

template <int EPI>
__global__ __launch_bounds__(512) void gemm512(const bf16_t* __restrict__ A,
                                               const bf16_t* __restrict__ B,
                                               float* __restrict__ C,
                                               bf16_t* __restrict__ qb,
                                               bf16_t* __restrict__ ktp,
                                               bf16_t* __restrict__ vt2,
                                               int M, int N, int K) {
  __shared__ __align__(16) bf16_t As[3][GBM * GBK];
  __shared__ __align__(16) bf16_t Bs[3][GBM * GBK];

  const int tid  = threadIdx.x;
  const int lane = tid & 63;
  const int w    = tid >> 6;          // 0..7
  const int wm   = (w >> 1) * 32;     // 4 row-groups of 32
  const int wn   = (w & 1) * 64;      // 2 col-groups of 64
  const int c    = lane & 15;
  const int quad = lane >> 4;
  const int m0   = blockIdx.y * GBM;
  const int n0   = blockIdx.x * GBN;

  f32x4 acc[2][4] = {};

  const bf16_t* Ab = A + (size_t)m0 * K;
  const bf16_t* Bb = B + (size_t)n0 * K;

  // staging: 512 16B chunks per matrix per K-step; thread -> chunk tid.
  // chunk p at LDS p*16B holds global (row=p>>2, kch=(p&3)^((p>>3)&3)).
  const int srow = tid >> 2;
  const int skch = (tid & 3) ^ ((tid >> 3) & 3);
  const int sbase = (w * 64) * 8;      // wave-uniform LDS element base

  auto stage = [&](int buf, int k0) {
    async_copy16(&As[buf][sbase], Ab + (size_t)srow * K + k0 + skch * 8);
    async_copy16(&Bs[buf][sbase], Bb + (size_t)srow * K + k0 + skch * 8);
  };

  auto compute = [&](int buf) {
    bf16x8 af[2], bfr[4];
#pragma unroll
    for (int mt = 0; mt < 2; ++mt) {
      int row = wm + mt * 16 + c;
      int kch = quad ^ ((row >> 1) & 3);
      af[mt] = *(const bf16x8*)&As[buf][(row * 4 + kch) * 8];
    }
#pragma unroll
    for (int nt = 0; nt < 4; ++nt) {
      int rowb = wn + nt * 16 + c;
      int kch = quad ^ ((rowb >> 1) & 3);
      bfr[nt] = *(const bf16x8*)&Bs[buf][(rowb * 4 + kch) * 8];
    }
#pragma unroll
    for (int mt = 0; mt < 2; ++mt)
#pragma unroll
      for (int nt = 0; nt < 4; ++nt)
        acc[mt][nt] = __builtin_amdgcn_mfma_f32_16x16x32_bf16(af[mt], bfr[nt], acc[mt][nt], 0, 0, 0);
  };

  const int NS = K / GBK;
  stage(0, 0);
  stage(1, GBK);
  int sc = 0, sp = 2;
  for (int k = 0; k < NS; ++k) {
    if (k + 1 < NS) {
      asm volatile("s_waitcnt vmcnt(2)" ::: "memory");  // oldest stage landed; newest stays in flight
    } else {
      asm volatile("s_waitcnt vmcnt(0)" ::: "memory");
    }
    __builtin_amdgcn_s_barrier();
    if (k + 2 < NS) stage(sp, (k + 2) * GBK);
    compute(sc);
    sc = (sc == 2) ? 0 : sc + 1;
    sp = (sp == 2) ? 0 : sp + 1;
  }

  if (EPI == 0) {
#pragma unroll
    for (int mt = 0; mt < 2; ++mt)
#pragma unroll
      for (int nt = 0; nt < 4; ++nt)
#pragma unroll
        for (int reg = 0; reg < 4; ++reg) {
          int row = m0 + wm + mt * 16 + quad * 4 + reg;
          int col = n0 + wn + nt * 16 + c;
          C[(size_t)row * N + col] = acc[mt][nt][reg];
        }
  } else {
    // fused qkv epilogue. wave covers one head's 64 cols: colb = n0+wn.
    const int colb = n0 + wn;
    if (colb < NHEAD * HD) {
      // ---- q: RoPE + 1/8 scale -> qb[s][h*64 + d]
      const int h = colb >> 6;
#pragma unroll
      for (int nt = 0; nt < 2; ++nt) {
        const int i = nt * 16 + c;
        const float invf = __expf(-(float)i * (9.210340371976184f / 32.0f));
#pragma unroll
        for (int mt = 0; mt < 2; ++mt)
#pragma unroll
          for (int reg = 0; reg < 4; ++reg) {
            const int s = m0 + wm + mt * 16 + quad * 4 + reg;
            float sn, cs;
            __sincosf((float)s * invf, &sn, &cs);
            const float x1 = acc[mt][nt][reg], x2 = acc[mt][nt + 2][reg];
            bf16_t* q = qb + (size_t)s * H_DIM + h * HD;
            q[i]      = (bf16_t)((x1 * cs - x2 * sn) * 0.125f);
            q[i + 32] = (bf16_t)((x2 * cs + x1 * sn) * 0.125f);
          }
      }
    } else if (colb < NHEAD * HD + KVH * HD) {
      // ---- k: RoPE -> ktp[kh][s][d]
      const int kh = (colb - NHEAD * HD) >> 6;
#pragma unroll
      for (int nt = 0; nt < 2; ++nt) {
        const int i = nt * 16 + c;
        const float invf = __expf(-(float)i * (9.210340371976184f / 32.0f));
#pragma unroll
        for (int mt = 0; mt < 2; ++mt)
#pragma unroll
          for (int reg = 0; reg < 4; ++reg) {
            const int s = m0 + wm + mt * 16 + quad * 4 + reg;
            float sn, cs;
            __sincosf((float)s * invf, &sn, &cs);
            const float x1 = acc[mt][nt][reg], x2 = acc[mt][nt + 2][reg];
            bf16_t* kd = ktp + ((size_t)kh * S_LEN + s) * HD;
            kd[i]      = (bf16_t)(x1 * cs - x2 * sn);
            kd[i + 32] = (bf16_t)(x2 * cs + x1 * sn);
          }
      }
    } else {
      // ---- v: transpose -> vt2[kh][d][s]
      const int kh = (colb - NHEAD * HD - KVH * HD) >> 6;
#pragma unroll
      for (int nt = 0; nt < 4; ++nt) {
        const int d = nt * 16 + c;
#pragma unroll
        for (int mt = 0; mt < 2; ++mt) {
          const int sr = m0 + wm + mt * 16 + quad * 4;
          bf16x4 pv;
#pragma unroll
          for (int reg = 0; reg < 4; ++reg) pv[reg] = (bf16_t)acc[mt][nt][reg];
          *(bf16x4*)&vt2[((size_t)kh * HD + d) * S_LEN + sr] = pv;
        }
      }
    }
  }
}

// ---------------- split-K MFMA flash ----------------
// Work item e in [0,1280): kh=e/160; i=e%160 -> band b (chunks per qt = b+1).
// Band 0 (i<16, single chunk): normalize and write attn directly (skip pbuf).
#define PSTR 72

__global__ __launch_bounds__(256) void flash_split(const bf16_t* __restrict__ qb,
                                                   const bf16_t* __restrict__ kt,
                                                   const bf16_t* __restrict__ vt2,
                                                   float* __restrict__ pbuf,
                                                   bf16_t* __restrict__ attn) {
  __shared__ __align__(16) bf16_t Ks[64 * 64];
  __shared__ __align__(16) bf16_t Vs[64 * 64];
  __shared__ __align__(16) bf16_t Ps[4][32 * PSTR];

  const int tid  = threadIdx.x;
  const int lane = tid & 63;
  const int w    = tid >> 6;
  const int e    = (int)gridDim.x - 1 - (int)blockIdx.x;  // big work first
  const int kh   = e / 160;
  const int i    = e - kh * 160;

  int qt, t_begin, t_end;
  {
    int T;
    if (i < 16)      { qt = i;                T = (qt >> 1) + 1; t_begin = 0;                 t_end = T; }
    else if (i < 48) { int r = i - 16; qt = 16 + (r >> 1); int ck = r & 1;
                       T = (qt >> 1) + 1; t_begin = (ck * T) >> 1;      t_end = ((ck + 1) * T) >> 1; }
    else if (i < 96) { int r = i - 48; qt = 32 + r / 3;    int ck = r % 3;
                       T = (qt >> 1) + 1; t_begin = (ck * T) / 3;       t_end = ((ck + 1) * T) / 3; }
    else             { int r = i - 96; qt = 48 + (r >> 2); int ck = r & 3;
                       T = (qt >> 1) + 1; t_begin = (ck * T) >> 2;      t_end = ((ck + 1) * T) >> 2; }
  }
  const int T     = (qt >> 1) + 1;
  const int s0    = qt * 32;
  const int h     = kh * 4 + w;
  const int c     = lane & 15;
  const int quad  = lane >> 4;

  bf16x8 qf[2][2];
#pragma unroll
  for (int rf = 0; rf < 2; ++rf)
#pragma unroll
    for (int ks = 0; ks < 2; ++ks)
      qf[rf][ks] = *(const bf16x8*)(qb + (size_t)(s0 + rf * 16 + c) * H_DIM + h * HD + ks * 32 + quad * 8);

  f32x4 acc[2][4] = {};
  float lsum[2] = {0.f, 0.f};

  const bf16_t* kbase = kt + (size_t)kh * S_LEN * HD;
  const bf16_t* vbase = vt2 + (size_t)kh * HD * S_LEN;

  int srow[2], skc[2], sbase[2];
#pragma unroll
  for (int i2 = 0; i2 < 2; ++i2) {
    int chunkbase = i2 * 256 + w * 64;
    int p = chunkbase + lane;
    sbase[i2] = chunkbase * 8;
    srow[i2]  = p >> 3;
    skc[i2]   = (p & 7) ^ (srow[i2] & 7);
  }

  for (int tile = t_begin; tile < t_end; ++tile) {
    const int t0 = tile * 64;
    __syncthreads();
#pragma unroll
    for (int i2 = 0; i2 < 2; ++i2) {
      async_copy16(&Ks[sbase[i2]], kbase + (size_t)(t0 + srow[i2]) * HD + skc[i2] * 8);
      async_copy16(&Vs[sbase[i2]], vbase + (size_t)srow[i2] * S_LEN + t0 + skc[i2] * 8);
    }
    __syncthreads();

    const bool masked = (tile == T - 1);
    int nact = 4;
    if (masked) { nact = ((s0 + 31 - t0) >> 4) + 1; if (nact > 4) nact = 4; }
    const int nkh = (nact + 1) >> 1;

#pragma unroll
    for (int rf = 0; rf < 2; ++rf) {
      for (int kt2 = 0; kt2 < nact; ++kt2) {
        f32x4 st = {};
#pragma unroll
        for (int ks = 0; ks < 2; ++ks) {
          bf16x8 kf = *(const bf16x8*)&Ks[((kt2 * 16 + c) * 8 + ((ks * 4 + quad) ^ (c & 7))) * 8];
          st = __builtin_amdgcn_mfma_f32_16x16x32_bf16(kf, qf[rf][ks], st, 0, 0, 0);
        }
        const int row = s0 + rf * 16 + c;
        bf16x4 pk;
#pragma unroll
        for (int reg = 0; reg < 4; ++reg) {
          const int key = t0 + kt2 * 16 + quad * 4 + reg;
          float p = __expf(st[reg] - 8.0f);
          if (masked && key > row) p = 0.f;
          pk[reg] = (bf16_t)p;
          lsum[rf] += p;
        }
        *(bf16x4*)&Ps[w][(rf * 16 + c) * PSTR + kt2 * 16 + quad * 4] = pk;
      }
      for (int kt2 = nact; kt2 < 2 * nkh; ++kt2) {
        bf16x4 z = {};
        *(bf16x4*)&Ps[w][(rf * 16 + c) * PSTR + kt2 * 16 + quad * 4] = z;
      }
    }

    for (int kh2 = 0; kh2 < nkh; ++kh2) {
      bf16x8 vf[4];
#pragma unroll
      for (int dt = 0; dt < 4; ++dt)
        vf[dt] = *(const bf16x8*)&Vs[((dt * 16 + c) * 8 + ((kh2 * 4 + quad) ^ (c & 7))) * 8];
#pragma unroll
      for (int rf = 0; rf < 2; ++rf) {
        bf16x8 pa = *(const bf16x8*)&Ps[w][(rf * 16 + c) * PSTR + kh2 * 32 + quad * 8];
#pragma unroll
        for (int dt = 0; dt < 4; ++dt)
          acc[rf][dt] = __builtin_amdgcn_mfma_f32_16x16x32_bf16(pa, vf[dt], acc[rf][dt], 0, 0, 0);
      }
    }
  }

#pragma unroll
  for (int rf = 0; rf < 2; ++rf) {
    lsum[rf] += __shfl_xor(lsum[rf], 16);
    lsum[rf] += __shfl_xor(lsum[rf], 32);
  }

  if (i < 16) {
    float* lbuf = (float*)&Ps[w][0];
#pragma unroll
    for (int rf = 0; rf < 2; ++rf) lbuf[rf * 16 + c] = lsum[rf];
    asm volatile("s_waitcnt lgkmcnt(0)" ::: "memory");
#pragma unroll
    for (int rf = 0; rf < 2; ++rf)
#pragma unroll
      for (int reg = 0; reg < 4; ++reg) {
        const float inv = 1.0f / lbuf[rf * 16 + quad * 4 + reg];
        const int row = s0 + rf * 16 + quad * 4 + reg;
#pragma unroll
        for (int dt = 0; dt < 4; ++dt)
          attn[(size_t)row * H_DIM + h * HD + dt * 16 + c] = (bf16_t)(acc[rf][dt][reg] * inv);
      }
  } else {
    float* ent = pbuf + (size_t)e * ENT_STRIDE;
#pragma unroll
    for (int rf = 0; rf < 2; ++rf) {
#pragma unroll
      for (int dt = 0; dt < 4; ++dt)
#pragma unroll
        for (int reg = 0; reg < 4; ++reg)
          ent[w * 2048 + (rf * 16 + quad * 4 + reg) * 64 + dt * 16 + c] = acc[rf][dt][reg];
      ent[8192 + w * 32 + rf * 16 + c] = lsum[rf];
    }
  }
}

// ---------------- reduce: sum chunks (qt>=16), normalize, write bf16 attn ----------------
__global__ __launch_bounds__(256) void flash_reduce(const float* __restrict__ pbuf,
                                                    bf16_t* __restrict__ attn) {
  const int kh = blockIdx.x / 48;
  const int qt = 16 + (blockIdx.x % 48);
  const int b  = qt >> 4;
  int base;
  if (b == 1)      base = kh * 160 + 16 + (qt - 16) * 2;
  else if (b == 2) base = kh * 160 + 48 + (qt - 32) * 3;
  else             base = kh * 160 + 96 + (qt - 48) * 4;
  const int nch = b + 1;

  const int t   = threadIdx.x;
  const int h2  = t >> 6;
  const int row = (t >> 1) & 31;
  const int dh  = t & 1;

  f32x4 o[8] = {};
  float l = 0.f;
  for (int ci = 0; ci < nch; ++ci) {
    const float* ent = pbuf + (size_t)(base + ci) * ENT_STRIDE;
    const float* p = ent + h2 * 2048 + row * 64 + dh * 32;
#pragma unroll
    for (int j = 0; j < 8; ++j) {
      f32x4 v = ((const f32x4*)p)[j];
      o[j][0] += v[0]; o[j][1] += v[1]; o[j][2] += v[2]; o[j][3] += v[3];
    }
    l += ent[8192 + h2 * 32 + row];
  }
  const float inv = 1.0f / l;
  bf16_t* dst = attn + (size_t)(qt * 32 + row) * H_DIM + (kh * 4 + h2) * 64 + dh * 32;
#pragma unroll
  for (int j = 0; j < 8; ++j) {
    bf16x4 ov;
    ov[0] = (bf16_t)(o[j][0] * inv); ov[1] = (bf16_t)(o[j][1] * inv);
    ov[2] = (bf16_t)(o[j][2] * inv); ov[3] = (bf16_t)(o[j][3] * inv);
    *(bf16x4*)(dst + j * 4) = ov;
  }
}

// ---------------- launch ----------------
extern "C" void kernel_launch(void* const* d_in, const int* in_sizes, int n_in,
                              void* d_out, int out_size, void* d_ws, size_t ws_size,
                              hipStream_t stream) {
  const float* x     = (const float*)d_in[0];
  const float* w_qkv = (const float*)d_in[1];
  const float* w_o   = (const float*)d_in[2];
  float* out = (float*)d_out;

  char* ws = (char*)d_ws;
  // Overlay region: x_bf + wqkv_bf (dead after gemm_qkv) / pbuf (live from flash_split).
  // Overlay sized to max(pbuf 42.6 MB, 21 MB).
  const size_t OVERLAY = (size_t)1280 * ENT_STRIDE * 4;  // 42.6 MB
  bf16_t* x_bf    = (bf16_t*)ws;
  bf16_t* wqkv_bf = (bf16_t*)(ws + (size_t)S_LEN * H_DIM * 2);
  float*  pbuf    = (float*)ws;
  size_t off = OVERLAY;
  bf16_t* wo_bf   = (bf16_t*)(ws + off); off += (size_t)H_DIM * H_DIM * 2;
  bf16_t* q_bf    = (bf16_t*)(ws + off); off += (size_t)S_LEN * H_DIM * 2;
  bf16_t* k_t     = (bf16_t*)(ws + off); off += (size_t)KVH * S_LEN * HD * 2;
  bf16_t* v_t2    = (bf16_t*)(ws + off); off += (size_t)KVH * S_LEN * HD * 2;
  bf16_t* attn    = (bf16_t*)(ws + off); off += (size_t)S_LEN * H_DIM * 2;

  const int ntot = (S_LEN * H_DIM + QKV_N * H_DIM + H_DIM * H_DIM) / 4;
  cast3_kernel<<<(ntot + 255) / 256, 256, 0, stream>>>(x, w_qkv, w_o, x_bf, wqkv_bf, wo_bf);

  gemm512<1><<<dim3(QKV_N / GBN, S_LEN / GBM), 512, 0, stream>>>(
      x_bf, wqkv_bf, nullptr, q_bf, k_t, v_t2, S_LEN, QKV_N, H_DIM);

  flash_split<<<1280, 256, 0, stream>>>(q_bf, k_t, v_t2, pbuf, attn);
  flash_reduce<<<384, 256, 0, stream>>>(pbuf, attn);

  gemm512<0><<<dim3(H_DIM / GBN, S_LEN / GBM), 512, 0, stream>>>(
      attn, wo_bf, out, nullptr, nullptr, nullptr, S_LEN, H_DIM, H_DIM);
}

// Round 8
// 216.913 us; speedup vs baseline: 1.2437x; 1.0754x over previous
//
#include <hip/hip_runtime.h>

// Attention block: qkv proj -> RoPE -> causal GQA flash attention -> out proj.
// B=1, S=2048, H=2048, NH=32, KVH=8, D=64, G=4.
// R8: gemm rework for the LDS-bandwidth regime: 8 waves/block, wave-pairs
//     split K (even/odd K32 halves, BK=64 iters, 1 barrier/K64), register
//     partials combined via LDS at end. Double-buffered staging (64KB) +
//     __launch_bounds__(512,4) -> 2 blocks (16 waves)/CU co-resident.

typedef __bf16 bf16_t;
typedef __attribute__((ext_vector_type(8))) __bf16 bf16x8;
typedef __attribute__((ext_vector_type(4))) __bf16 bf16x4;
typedef __attribute__((ext_vector_type(4))) float f32x4;

#define S_LEN 2048
#define H_DIM 2048
#define NHEAD 32
#define KVH 8
#define HD 64
#define QKV_N 3072  // (NH + 2*KVH) * D

#define ENT_STRIDE 8320  // floats per partial entry: 4h*32r*64d + 4h*32r l

// ---------------- fused cast fp32 -> bf16 (x, w_qkv, w_o) ----------------
__global__ void cast3_kernel(const float* __restrict__ x, const float* __restrict__ wq,
                             const float* __restrict__ wo, bf16_t* __restrict__ xb,
                             bf16_t* __restrict__ wqb, bf16_t* __restrict__ wob) {
  int i = blockIdx.x * blockDim.x + threadIdx.x;
  const int n1 = S_LEN * H_DIM / 4, n2 = QKV_N * H_DIM / 4, n3 = H_DIM * H_DIM / 4;
  const float* src; bf16_t* dst; int j;
  if (i < n1)           { src = x;  dst = xb;  j = i; }
  else if (i < n1 + n2) { src = wq; dst = wqb; j = i - n1; }
  else if (i < n1 + n2 + n3) { src = wo; dst = wob; j = i - n1 - n2; }
  else return;
  float4 v = ((const float4*)src)[j];
  bf16x4 o;
  o.x = (bf16_t)v.x; o.y = (bf16_t)v.y; o.z = (bf16_t)v.z; o.w = (bf16_t)v.w;
  ((bf16x4*)dst)[j] = o;
}

// ---------------- async 16B global -> LDS ----------------
__device__ __forceinline__ void async_copy16(bf16_t* lds_base, const bf16_t* g) {
  __builtin_amdgcn_global_load_lds(
      (const __attribute__((address_space(1))) unsigned int*)g,
      (__attribute__((address_space(3))) unsigned int*)lds_base, 16, 0, 0);
}

// ---------------- GEMM: C[M,N] = A[M,K] * B[N,K]^T (bf16 in) ----------------
// 128x128 tile, 512 threads = 8 waves. Wave-pair (wq, wq+4) owns one 64x64
// C-subtile (2x2 grid); group gw=w>>2 processes K32-half gw of each BK=64
// iteration. Double-buffered async staging, 1 raw barrier + vmcnt(0) per iter.
// Partials combined through LDS after the loop.
// EPI=0: C fp32 plain.  EPI=1: fused qkv epilogue (RoPE q/k, V transpose).
#define GBM 128
#define GBN 128

template <int EPI>
__global__ __launch_bounds__(512, 4) void gemm_sk(const bf16_t* __restrict__ A,
                                                  const bf16_t* __restrict__ B,
                                                  float* __restrict__ C,
                                                  bf16_t* __restrict__ qb,
                                                  bf16_t* __restrict__ ktp,
                                                  bf16_t* __restrict__ vt2,
                                                  int M, int N, int K) {
  __shared__ __align__(16) bf16_t As[2][GBM * 64];
  __shared__ __align__(16) bf16_t Bs[2][GBM * 64];

  const int tid  = threadIdx.x;
  const int lane = tid & 63;
  const int w    = tid >> 6;          // 0..7
  const int wq   = w & 3;             // pair id / subtile
  const int gw   = w >> 2;            // K32 group
  const int wm   = (wq >> 1) * 64;
  const int wn   = (wq & 1) * 64;
  const int c    = lane & 15;
  const int quad = lane >> 4;
  const int m0   = blockIdx.y * GBM;
  const int n0   = blockIdx.x * GBN;

  f32x4 acc[4][4] = {};

  const bf16_t* Ab = A + (size_t)m0 * K;
  const bf16_t* Bb = B + (size_t)n0 * K;

  // staging: per matrix per iter, 1024 16B chunks (128 rows x 8 chunks of 8 elems).
  // chunk p: row=p>>3, kc=(p&7)^(row&7). thread handles p = i*512 + tid.
  int srow[2], skc[2], sb[2];
#pragma unroll
  for (int i = 0; i < 2; ++i) {
    int p = i * 512 + tid;
    srow[i] = p >> 3;
    skc[i]  = (p & 7) ^ (srow[i] & 7);
    sb[i]   = (i * 512 + w * 64) * 8;   // wave-uniform element base
  }

  auto stage = [&](int buf, int k0) {
#pragma unroll
    for (int i = 0; i < 2; ++i) {
      async_copy16(&As[buf][sb[i]], Ab + (size_t)srow[i] * K + k0 + skc[i] * 8);
      async_copy16(&Bs[buf][sb[i]], Bb + (size_t)srow[i] * K + k0 + skc[i] * 8);
    }
  };

  auto compute = [&](int buf) {
    bf16x8 af[4], bfr[4];
#pragma unroll
    for (int mt = 0; mt < 4; ++mt) {
      int row = wm + mt * 16 + c;
      af[mt] = *(const bf16x8*)&As[buf][(row * 8 + ((gw * 4 + quad) ^ (row & 7))) * 8];
    }
#pragma unroll
    for (int nt = 0; nt < 4; ++nt) {
      int rowb = wn + nt * 16 + c;
      bfr[nt] = *(const bf16x8*)&Bs[buf][(rowb * 8 + ((gw * 4 + quad) ^ (rowb & 7))) * 8];
    }
#pragma unroll
    for (int mt = 0; mt < 4; ++mt)
#pragma unroll
      for (int nt = 0; nt < 4; ++nt)
        acc[mt][nt] = __builtin_amdgcn_mfma_f32_16x16x32_bf16(af[mt], bfr[nt], acc[mt][nt], 0, 0, 0);
  };

  const int NI = K >> 6;   // BK=64 iterations
  stage(0, 0);
  int buf = 0;
  for (int it = 0; it < NI; ++it) {
    asm volatile("s_waitcnt vmcnt(0)" ::: "memory");  // cur buf staged (only 4 own loads outstanding)
    __builtin_amdgcn_s_barrier();                     // all waves done reading buf^1 (prev iter)
    if (it + 1 < NI) stage(buf ^ 1, (it + 1) << 6);
    compute(buf);
    buf ^= 1;
  }

  // combine wave-pair partials through LDS (64 KB exchange over dead staging bufs)
  __syncthreads();
  float* xch = (float*)&As[0][0];
  if (gw == 1) {
#pragma unroll
    for (int t16 = 0; t16 < 16; ++t16)
      *(f32x4*)&xch[wq * 4096 + (t16 * 64 + lane) * 4] = acc[t16 >> 2][t16 & 3];
  }
  __syncthreads();
  if (gw == 0) {
#pragma unroll
    for (int t16 = 0; t16 < 16; ++t16) {
      f32x4 o = *(const f32x4*)&xch[wq * 4096 + (t16 * 64 + lane) * 4];
      acc[t16 >> 2][t16 & 3] += o;
    }

    if (EPI == 0) {
#pragma unroll
      for (int mt = 0; mt < 4; ++mt)
#pragma unroll
        for (int nt = 0; nt < 4; ++nt)
#pragma unroll
          for (int reg = 0; reg < 4; ++reg) {
            int row = m0 + wm + mt * 16 + quad * 4 + reg;
            int col = n0 + wn + nt * 16 + c;
            C[(size_t)row * N + col] = acc[mt][nt][reg];
          }
    } else {
      // fused qkv epilogue: wave covers one head's 64 cols.
      const int colb = n0 + wn;
      if (colb < NHEAD * HD) {
        const int h = colb >> 6;
#pragma unroll
        for (int nt = 0; nt < 2; ++nt) {
          const int i = nt * 16 + c;
          const float invf = __expf(-(float)i * (9.210340371976184f / 32.0f));
#pragma unroll
          for (int mt = 0; mt < 4; ++mt)
#pragma unroll
            for (int reg = 0; reg < 4; ++reg) {
              const int s = m0 + wm + mt * 16 + quad * 4 + reg;
              float sn, cs;
              __sincosf((float)s * invf, &sn, &cs);
              const float x1 = acc[mt][nt][reg], x2 = acc[mt][nt + 2][reg];
              bf16_t* q = qb + (size_t)s * H_DIM + h * HD;
              q[i]      = (bf16_t)((x1 * cs - x2 * sn) * 0.125f);
              q[i + 32] = (bf16_t)((x2 * cs + x1 * sn) * 0.125f);
            }
        }
      } else if (colb < NHEAD * HD + KVH * HD) {
        const int kh = (colb - NHEAD * HD) >> 6;
#pragma unroll
        for (int nt = 0; nt < 2; ++nt) {
          const int i = nt * 16 + c;
          const float invf = __expf(-(float)i * (9.210340371976184f / 32.0f));
#pragma unroll
          for (int mt = 0; mt < 4; ++mt)
#pragma unroll
            for (int reg = 0; reg < 4; ++reg) {
              const int s = m0 + wm + mt * 16 + quad * 4 + reg;
              float sn, cs;
              __sincosf((float)s * invf, &sn, &cs);
              const float x1 = acc[mt][nt][reg], x2 = acc[mt][nt + 2][reg];
              bf16_t* kd = ktp + ((size_t)kh * S_LEN + s) * HD;
              kd[i]      = (bf16_t)(x1 * cs - x2 * sn);
              kd[i + 32] = (bf16_t)(x2 * cs + x1 * sn);
            }
        }
      } else {
        const int kh = (colb - NHEAD * HD - KVH * HD) >> 6;
#pragma unroll
        for (int nt = 0; nt < 4; ++nt) {
          const int d = nt * 16 + c;
#pragma unroll
          for (int mt = 0; mt < 4; ++mt) {
            const int sr = m0 + wm + mt * 16 + quad * 4;
            bf16x4 pv;
#pragma unroll
            for (int reg = 0; reg < 4; ++reg) pv[reg] = (bf16_t)acc[mt][nt][reg];
            *(bf16x4*)&vt2[((size_t)kh * HD + d) * S_LEN + sr] = pv;
          }
        }
      }
    }
  }
}

// ---------------- split-K MFMA flash ----------------
#define PSTR 72

__global__ __launch_bounds__(256) void flash_split(const bf16_t* __restrict__ qb,
                                                   const bf16_t* __restrict__ kt,
                                                   const bf16_t* __restrict__ vt2,
                                                   float* __restrict__ pbuf,
                                                   bf16_t* __restrict__ attn) {
  __shared__ __align__(16) bf16_t Ks[64 * 64];
  __shared__ __align__(16) bf16_t Vs[64 * 64];
  __shared__ __align__(16) bf16_t Ps[4][32 * PSTR];

  const int tid  = threadIdx.x;
  const int lane = tid & 63;
  const int w    = tid >> 6;
  const int e    = (int)gridDim.x - 1 - (int)blockIdx.x;
  const int kh   = e / 160;
  const int i    = e - kh * 160;

  int qt, t_begin, t_end;
  {
    int T;
    if (i < 16)      { qt = i;                T = (qt >> 1) + 1; t_begin = 0;                 t_end = T; }
    else if (i < 48) { int r = i - 16; qt = 16 + (r >> 1); int ck = r & 1;
                       T = (qt >> 1) + 1; t_begin = (ck * T) >> 1;      t_end = ((ck + 1) * T) >> 1; }
    else if (i < 96) { int r = i - 48; qt = 32 + r / 3;    int ck = r % 3;
                       T = (qt >> 1) + 1; t_begin = (ck * T) / 3;       t_end = ((ck + 1) * T) / 3; }
    else             { int r = i - 96; qt = 48 + (r >> 2); int ck = r & 3;
                       T = (qt >> 1) + 1; t_begin = (ck * T) >> 2;      t_end = ((ck + 1) * T) >> 2; }
  }
  const int T     = (qt >> 1) + 1;
  const int s0    = qt * 32;
  const int h     = kh * 4 + w;
  const int c     = lane & 15;
  const int quad  = lane >> 4;

  bf16x8 qf[2][2];
#pragma unroll
  for (int rf = 0; rf < 2; ++rf)
#pragma unroll
    for (int ks = 0; ks < 2; ++ks)
      qf[rf][ks] = *(const bf16x8*)(qb + (size_t)(s0 + rf * 16 + c) * H_DIM + h * HD + ks * 32 + quad * 8);

  f32x4 acc[2][4] = {};
  float lsum[2] = {0.f, 0.f};

  const bf16_t* kbase = kt + (size_t)kh * S_LEN * HD;
  const bf16_t* vbase = vt2 + (size_t)kh * HD * S_LEN;

  int srow[2], skc[2], sbase[2];
#pragma unroll
  for (int i2 = 0; i2 < 2; ++i2) {
    int chunkbase = i2 * 256 + w * 64;
    int p = chunkbase + lane;
    sbase[i2] = chunkbase * 8;
    srow[i2]  = p >> 3;
    skc[i2]   = (p & 7) ^ (srow[i2] & 7);
  }

  for (int tile = t_begin; tile < t_end; ++tile) {
    const int t0 = tile * 64;
    __syncthreads();
#pragma unroll
    for (int i2 = 0; i2 < 2; ++i2) {
      async_copy16(&Ks[sbase[i2]], kbase + (size_t)(t0 + srow[i2]) * HD + skc[i2] * 8);
      async_copy16(&Vs[sbase[i2]], vbase + (size_t)srow[i2] * S_LEN + t0 + skc[i2] * 8);
    }
    __syncthreads();

    const bool masked = (tile == T - 1);
    int nact = 4;
    if (masked) { nact = ((s0 + 31 - t0) >> 4) + 1; if (nact > 4) nact = 4; }
    const int nkh = (nact + 1) >> 1;

#pragma unroll
    for (int rf = 0; rf < 2; ++rf) {
      for (int kt2 = 0; kt2 < nact; ++kt2) {
        f32x4 st = {};
#pragma unroll
        for (int ks = 0; ks < 2; ++ks) {
          bf16x8 kf = *(const bf16x8*)&Ks[((kt2 * 16 + c) * 8 + ((ks * 4 + quad) ^ (c & 7))) * 8];
          st = __builtin_amdgcn_mfma_f32_16x16x32_bf16(kf, qf[rf][ks], st, 0, 0, 0);
        }
        const int row = s0 + rf * 16 + c;
        bf16x4 pk;
#pragma unroll
        for (int reg = 0; reg < 4; ++reg) {
          const int key = t0 + kt2 * 16 + quad * 4 + reg;
          float p = __expf(st[reg] - 8.0f);
          if (masked && key > row) p = 0.f;
          pk[reg] = (bf16_t)p;
          lsum[rf] += p;
        }
        *(bf16x4*)&Ps[w][(rf * 16 + c) * PSTR + kt2 * 16 + quad * 4] = pk;
      }
      for (int kt2 = nact; kt2 < 2 * nkh; ++kt2) {
        bf16x4 z = {};
        *(bf16x4*)&Ps[w][(rf * 16 + c) * PSTR + kt2 * 16 + quad * 4] = z;
      }
    }

    for (int kh2 = 0; kh2 < nkh; ++kh2) {
      bf16x8 vf[4];
#pragma unroll
      for (int dt = 0; dt < 4; ++dt)
        vf[dt] = *(const bf16x8*)&Vs[((dt * 16 + c) * 8 + ((kh2 * 4 + quad) ^ (c & 7))) * 8];
#pragma unroll
      for (int rf = 0; rf < 2; ++rf) {
        bf16x8 pa = *(const bf16x8*)&Ps[w][(rf * 16 + c) * PSTR + kh2 * 32 + quad * 8];
#pragma unroll
        for (int dt = 0; dt < 4; ++dt)
          acc[rf][dt] = __builtin_amdgcn_mfma_f32_16x16x32_bf16(pa, vf[dt], acc[rf][dt], 0, 0, 0);
      }
    }
  }

#pragma unroll
  for (int rf = 0; rf < 2; ++rf) {
    lsum[rf] += __shfl_xor(lsum[rf], 16);
    lsum[rf] += __shfl_xor(lsum[rf], 32);
  }

  if (i < 16) {
    float* lbuf = (float*)&Ps[w][0];
#pragma unroll
    for (int rf = 0; rf < 2; ++rf) lbuf[rf * 16 + c] = lsum[rf];
    asm volatile("s_waitcnt lgkmcnt(0)" ::: "memory");
#pragma unroll
    for (int rf = 0; rf < 2; ++rf)
#pragma unroll
      for (int reg = 0; reg < 4; ++reg) {
        const float inv = 1.0f / lbuf[rf * 16 + quad * 4 + reg];
        const int row = s0 + rf * 16 + quad * 4 + reg;
#pragma unroll
        for (int dt = 0; dt < 4; ++dt)
          attn[(size_t)row * H_DIM + h * HD + dt * 16 + c] = (bf16_t)(acc[rf][dt][reg] * inv);
      }
  } else {
    float* ent = pbuf + (size_t)e * ENT_STRIDE;
#pragma unroll
    for (int rf = 0; rf < 2; ++rf) {
#pragma unroll
      for (int dt = 0; dt < 4; ++dt)
#pragma unroll
        for (int reg = 0; reg < 4; ++reg)
          ent[w * 2048 + (rf * 16 + quad * 4 + reg) * 64 + dt * 16 + c] = acc[rf][dt][reg];
      ent[8192 + w * 32 + rf * 16 + c] = lsum[rf];
    }
  }
}

// ---------------- reduce: sum chunks (qt>=16), normalize, write bf16 attn ----------------
__global__ __launch_bounds__(256) void flash_reduce(const float* __restrict__ pbuf,
                                                    bf16_t* __restrict__ attn) {
  const int kh = blockIdx.x / 48;
  const int qt = 16 + (blockIdx.x % 48);
  const int b  = qt >> 4;
  int base;
  if (b == 1)      base = kh * 160 + 16 + (qt - 16) * 2;
  else if (b == 2) base = kh * 160 + 48 + (qt - 32) * 3;
  else             base = kh * 160 + 96 + (qt - 48) * 4;
  const int nch = b + 1;

  const int t   = threadIdx.x;
  const int h2  = t >> 6;
  const int row = (t >> 1) & 31;
  const int dh  = t & 1;

  f32x4 o[8] = {};
  float l = 0.f;
  for (int ci = 0; ci < nch; ++ci) {
    const float* ent = pbuf + (size_t)(base + ci) * ENT_STRIDE;
    const float* p = ent + h2 * 2048 + row * 64 + dh * 32;
#pragma unroll
    for (int j = 0; j < 8; ++j) {
      f32x4 v = ((const f32x4*)p)[j];
      o[j][0] += v[0]; o[j][1] += v[1]; o[j][2] += v[2]; o[j][3] += v[3];
    }
    l += ent[8192 + h2 * 32 + row];
  }
  const float inv = 1.0f / l;
  bf16_t* dst = attn + (size_t)(qt * 32 + row) * H_DIM + (kh * 4 + h2) * 64 + dh * 32;
#pragma unroll
  for (int j = 0; j < 8; ++j) {
    bf16x4 ov;
    ov[0] = (bf16_t)(o[j][0] * inv); ov[1] = (bf16_t)(o[j][1] * inv);
    ov[2] = (bf16_t)(o[j][2] * inv); ov[3] = (bf16_t)(o[j][3] * inv);
    *(bf16x4*)(dst + j * 4) = ov;
  }
}

// ---------------- launch ----------------
extern "C" void kernel_launch(void* const* d_in, const int* in_sizes, int n_in,
                              void* d_out, int out_size, void* d_ws, size_t ws_size,
                              hipStream_t stream) {
  const float* x     = (const float*)d_in[0];
  const float* w_qkv = (const float*)d_in[1];
  const float* w_o   = (const float*)d_in[2];
  float* out = (float*)d_out;

  char* ws = (char*)d_ws;
  const size_t OVERLAY = (size_t)1280 * ENT_STRIDE * 4;  // 42.6 MB
  bf16_t* x_bf    = (bf16_t*)ws;
  bf16_t* wqkv_bf = (bf16_t*)(ws + (size_t)S_LEN * H_DIM * 2);
  float*  pbuf    = (float*)ws;
  size_t off = OVERLAY;
  bf16_t* wo_bf   = (bf16_t*)(ws + off); off += (size_t)H_DIM * H_DIM * 2;
  bf16_t* q_bf    = (bf16_t*)(ws + off); off += (size_t)S_LEN * H_DIM * 2;
  bf16_t* k_t     = (bf16_t*)(ws + off); off += (size_t)KVH * S_LEN * HD * 2;
  bf16_t* v_t2    = (bf16_t*)(ws + off); off += (size_t)KVH * S_LEN * HD * 2;
  bf16_t* attn    = (bf16_t*)(ws + off); off += (size_t)S_LEN * H_DIM * 2;

  const int ntot = (S_LEN * H_DIM + QKV_N * H_DIM + H_DIM * H_DIM) / 4;
  cast3_kernel<<<(ntot + 255) / 256, 256, 0, stream>>>(x, w_qkv, w_o, x_bf, wqkv_bf, wo_bf);

  gemm_sk<1><<<dim3(QKV_N / GBN, S_LEN / GBM), 512, 0, stream>>>(
      x_bf, wqkv_bf, nullptr, q_bf, k_t, v_t2, S_LEN, QKV_N, H_DIM);

  flash_split<<<1280, 256, 0, stream>>>(q_bf, k_t, v_t2, pbuf, attn);
  flash_reduce<<<384, 256, 0, stream>>>(pbuf, attn);

  gemm_sk<0><<<dim3(H_DIM / GBN, S_LEN / GBM), 512, 0, stream>>>(
      attn, wo_bf, out, nullptr, nullptr, nullptr, S_LEN, H_DIM, H_DIM);
}